// Round 3
// baseline (241.285 us; speedup 1.0000x reference)
//
#include <hip/hip_runtime.h>
#include <hip/hip_bf16.h>
#include <math.h>

#define T_DIM 2048
#define D_DIM 2048
#define H_DIM 16
#define C_DIM 128

typedef __bf16 bf16;
typedef __attribute__((ext_vector_type(8))) __bf16 bf16x8;
typedef __attribute__((ext_vector_type(4))) __bf16 bf16x4;
typedef __attribute__((ext_vector_type(2))) __bf16 bf16x2;
typedef __attribute__((ext_vector_type(4))) float f32x4;

__device__ __forceinline__ void gload_lds16(const void* g, void* l) {
  __builtin_amdgcn_global_load_lds((__attribute__((address_space(1))) void*)g,
                                   (__attribute__((address_space(3))) void*)l,
                                   16, 0, 0);
}

// ---------------- fp32 -> bf16 conversion (vectorized) ----------------
__global__ __launch_bounds__(256) void cvt_f32_to_bf16(
    const float* __restrict__ src, bf16* __restrict__ dst, int n4)
{
  int i = blockIdx.x * blockDim.x + threadIdx.x;
  int stride = gridDim.x * blockDim.x;
  for (; i < n4; i += stride) {
    float4 v = reinterpret_cast<const float4*>(src)[i];
    bf16x4 o;
    o[0] = (bf16)v.x; o[1] = (bf16)v.y; o[2] = (bf16)v.z; o[3] = (bf16)v.w;
    reinterpret_cast<bf16x4*>(dst)[i] = o;
  }
}

// ---------------- GEMM: C(MxN) = A(MxK) @ B(NxK)^T + bias, fp32 out ----------------
__global__ __launch_bounds__(256) void gemm_bt_bias(
    const bf16* __restrict__ A, const bf16* __restrict__ B,
    const float* __restrict__ bias, float* __restrict__ C,
    int M, int N, int K)
{
  __shared__ __align__(16) bf16 As[128 * 32];
  __shared__ __align__(16) bf16 Bs[128 * 32];
  const int tid = threadIdx.x;
  const int lane = tid & 63;
  const int w = tid >> 6;
  const int wm = (w >> 1) * 64, wn = (w & 1) * 64;
  const int g = lane >> 4;
  const int r16 = lane & 15;
  const int bm = blockIdx.y, bn = blockIdx.x;

  f32x4 acc[4][4] = {};

  const size_t Abase = (size_t)(bm * 128) * K;
  const size_t Bbase = (size_t)(bn * 128) * K;

  for (int k0 = 0; k0 < K; k0 += 32) {
#pragma unroll
    for (int c = 0; c < 2; ++c) {
      int e = c * 256 + tid;
      int row = e >> 2, col = (e & 3) * 8;
      gload_lds16(A + Abase + (size_t)row * K + k0 + col, (char*)As + (size_t)e * 16);
      gload_lds16(B + Bbase + (size_t)row * K + k0 + col, (char*)Bs + (size_t)e * 16);
    }
    __syncthreads();
    bf16x8 a[4], b[4];
#pragma unroll
    for (int m = 0; m < 4; ++m)
      a[m] = *reinterpret_cast<const bf16x8*>(&As[(wm + m * 16 + r16) * 32 + g * 8]);
#pragma unroll
    for (int n = 0; n < 4; ++n)
      b[n] = *reinterpret_cast<const bf16x8*>(&Bs[(wn + n * 16 + r16) * 32 + g * 8]);
#pragma unroll
    for (int m = 0; m < 4; ++m)
#pragma unroll
      for (int n = 0; n < 4; ++n)
        acc[m][n] = __builtin_amdgcn_mfma_f32_16x16x32_bf16(a[m], b[n], acc[m][n], 0, 0, 0);
    __syncthreads();
  }

#pragma unroll
  for (int m = 0; m < 4; ++m) {
    int row0 = bm * 128 + wm + m * 16 + g * 4;
#pragma unroll
    for (int n = 0; n < 4; ++n) {
      int col = bn * 128 + wn + n * 16 + r16;
      float bv = bias[col];
#pragma unroll
      for (int rr = 0; rr < 4; ++rr)
        C[(size_t)(row0 + rr) * N + col] = acc[m][n][rr] + bv;
    }
  }
}

// ---------------- LayerNorm + RoPE + pack q/k to bf16 [h][t][c] ----------------
__global__ __launch_bounds__(256) void ln_rope_kernel(
    const float* __restrict__ qkv, const float* __restrict__ qw,
    const float* __restrict__ kw, bf16* __restrict__ qo, bf16* __restrict__ ko)
{
  const int tid = threadIdx.x;
  const int lane = tid & 63;
  const int wid = blockIdx.x * 4 + (tid >> 6);
  const int h = wid >> 11;          // / T
  const int t = wid & (T_DIM - 1);
  const int c0 = lane * 2;

  float inv_freq = exp2f(-13.287712379549449f * (float)c0 * (1.0f / 128.0f));
  float fr = (float)t * inv_freq;
  float sn = sinf(fr), cs = cosf(fr);
  const float scaleq = 0.08838834764831845f; // 1/sqrt(128)

#pragma unroll
  for (int which = 0; which < 2; ++which) {
    const float* base = qkv + (size_t)t * (3 * D_DIM) + which * D_DIM + h * C_DIM;
    float2 v = *reinterpret_cast<const float2*>(base + c0);
    float s = v.x + v.y;
#pragma unroll
    for (int m = 32; m; m >>= 1) s += __shfl_xor(s, m);
    float mu = s * (1.0f / 128.0f);
    float d0 = v.x - mu, d1 = v.y - mu;
    float ss = d0 * d0 + d1 * d1;
#pragma unroll
    for (int m = 32; m; m >>= 1) ss += __shfl_xor(ss, m);
    float rstd = rsqrtf(ss * (1.0f / 128.0f) + 1e-6f);
    const float* wgt = which ? kw : qw;
    float x0 = d0 * rstd * wgt[c0], x1 = d1 * rstd * wgt[c0 + 1];
    float o0 = x0 * cs - x1 * sn;
    float o1 = x1 * cs + x0 * sn;
    if (!which) { o0 *= scaleq; o1 *= scaleq; }
    bf16* out = (which ? ko : qo) + ((size_t)h * T_DIM + t) * C_DIM + c0;
    bf16x2 ob; ob[0] = (bf16)o0; ob[1] = (bf16)o1;
    *reinterpret_cast<bf16x2*>(out) = ob;
  }
}

// ---------------- V transpose: qkv v-part (t,c) -> vt bf16 [h][c][t] ----------------
__global__ __launch_bounds__(256) void v_transpose_kernel(
    const float* __restrict__ qkv, bf16* __restrict__ vt)
{
  __shared__ bf16 tile[32][33];
  const int h = blockIdx.z;
  const int t0 = blockIdx.x * 32, c0 = blockIdx.y * 32;
  const int tx = threadIdx.x, ty = threadIdx.y;
#pragma unroll
  for (int i = 0; i < 4; ++i) {
    int t = t0 + ty + i * 8;
    tile[ty + i * 8][tx] =
        (bf16)qkv[(size_t)t * (3 * D_DIM) + 2 * D_DIM + h * C_DIM + c0 + tx];
  }
  __syncthreads();
#pragma unroll
  for (int i = 0; i < 4; ++i) {
    int c = c0 + ty + i * 8;
    vt[((size_t)h * C_DIM + c) * T_DIM + t0 + tx] = tile[tx][ty + i * 8];
  }
}

// ---------------- Flash attention (causal), KV-split flash-decoding ----------------
// Blocks: x in [0,48), y = head.
//   b <  32: qb = 16 + (b>>1), s = b&1, KV tiles [s*16, s?qb+1:16)  -> partial U/ML
//   b >= 32: qb = 47 - b (15..0), full range [0, qb+1)              -> direct AO
// K (64x128) and V^T (128x64) staged in LDS, double-buffered, XOR-swizzled via
// pre-swizzled global source + matching XOR on reads (rule #21).
__global__ __launch_bounds__(256) void attn_kernel(
    const bf16* __restrict__ Q, const bf16* __restrict__ K,
    const bf16* __restrict__ VT, bf16* __restrict__ AO,
    float* __restrict__ U, float* __restrict__ ML)
{
  __shared__ __align__(16) bf16 Ks[2][64 * 128];   // 32 KB
  __shared__ __align__(16) bf16 Vs[2][128 * 64];   // 32 KB
  __shared__ __align__(16) bf16 p_lds[4][16 * 64]; //  8 KB
  const int tid = threadIdx.x;
  const int lane = tid & 63;
  const int w = tid >> 6;
  const int g = lane >> 4, r16 = lane & 15;
  const int h = blockIdx.y;
  const int b = blockIdx.x;

  int qb, kb0, kb1, s;
  if (b < 32) { qb = 16 + (b >> 1); s = b & 1; kb0 = s * 16; kb1 = s ? (qb + 1) : 16; }
  else        { qb = 47 - b;        s = -1;    kb0 = 0;      kb1 = qb + 1; }
  const int qr0 = qb * 64 + w * 16;

  const bf16* Qh = Q + (size_t)h * T_DIM * C_DIM;
  const bf16* Kh = K + (size_t)h * T_DIM * C_DIM;
  const bf16* Vh = VT + (size_t)h * C_DIM * T_DIM;

  bf16x8 qf[4];
#pragma unroll
  for (int kk = 0; kk < 4; ++kk)
    qf[kk] = *reinterpret_cast<const bf16x8*>(
        &Qh[(size_t)(qr0 + r16) * C_DIM + kk * 32 + g * 8]);

  float mrow[4] = {-INFINITY, -INFINITY, -INFINITY, -INFINITY};
  float lrow[4] = {0.f, 0.f, 0.f, 0.f};
  f32x4 o[8] = {};

  // stage K(64x128) + V(128x64) tile kb into buf; 8 x 16B per thread.
  auto stage = [&](int buf, int kb) {
    const bf16* Kt = Kh + (size_t)(kb * 64) * C_DIM;
    const bf16* Vt = Vh + kb * 64;
#pragma unroll
    for (int i = 0; i < 4; ++i) {
      int e = i * 256 + tid;
      int r = e >> 4, p = e & 15, j = p ^ (r & 7);
      gload_lds16(Kt + r * C_DIM + j * 8, (char*)&Ks[buf][0] + (size_t)e * 16);
    }
#pragma unroll
    for (int i = 0; i < 4; ++i) {
      int e = i * 256 + tid;
      int r = e >> 3, p = e & 7, j = p ^ (r & 7);
      gload_lds16(Vt + (size_t)r * T_DIM + j * 8, (char*)&Vs[buf][0] + (size_t)e * 16);
    }
  };

  stage(0, kb0);
  __syncthreads();  // drains vmcnt: first tile ready
  int buf = 0;

  for (int kb = kb0; kb < kb1; ++kb) {
    if (kb + 1 < kb1) stage(buf ^ 1, kb + 1);  // latency hides under compute

    // ---- QK^T from LDS (swizzled reads) ----
    f32x4 sacc[4] = {};
    __builtin_amdgcn_s_setprio(1);
#pragma unroll
    for (int n = 0; n < 4; ++n) {
      int kr = n * 16 + r16;
      const bf16* kbase = &Ks[buf][kr << 7];
#pragma unroll
      for (int kk = 0; kk < 4; ++kk) {
        bf16x8 kf = *reinterpret_cast<const bf16x8*>(
            kbase + (((kk * 4 + g) ^ (kr & 7)) << 3));
        sacc[n] = __builtin_amdgcn_mfma_f32_16x16x32_bf16(qf[kk], kf, sacc[n], 0, 0, 0);
      }
    }
    __builtin_amdgcn_s_setprio(0);
    // causal mask (auto-skipped for non-diagonal tiles)
    if (!(kb * 64 + 63 <= qr0)) {
#pragma unroll
      for (int n = 0; n < 4; ++n) {
        int key = kb * 64 + n * 16 + r16;
#pragma unroll
        for (int rr = 0; rr < 4; ++rr) {
          int qrow = qr0 + g * 4 + rr;
          if (key > qrow) sacc[n][rr] = -3.0e38f;
        }
      }
    }
    // ---- online softmax (per q-row; reduce across 16-lane groups) ----
    float alpha[4];
#pragma unroll
    for (int rr = 0; rr < 4; ++rr) {
      float mx = fmaxf(fmaxf(sacc[0][rr], sacc[1][rr]),
                       fmaxf(sacc[2][rr], sacc[3][rr]));
      mx = fmaxf(mx, __shfl_xor(mx, 1));
      mx = fmaxf(mx, __shfl_xor(mx, 2));
      mx = fmaxf(mx, __shfl_xor(mx, 4));
      mx = fmaxf(mx, __shfl_xor(mx, 8));
      float mnew = fmaxf(mrow[rr], mx);
      alpha[rr] = __expf(mrow[rr] - mnew);
      mrow[rr] = mnew;
      float ps = 0.f;
#pragma unroll
      for (int n = 0; n < 4; ++n) {
        float p = __expf(sacc[n][rr] - mnew);
        sacc[n][rr] = p;
        ps += p;
      }
      ps += __shfl_xor(ps, 1); ps += __shfl_xor(ps, 2);
      ps += __shfl_xor(ps, 4); ps += __shfl_xor(ps, 8);
      lrow[rr] = lrow[rr] * alpha[rr] + ps;
    }
#pragma unroll
    for (int nc = 0; nc < 8; ++nc)
#pragma unroll
      for (int rr = 0; rr < 4; ++rr)
        o[nc][rr] *= alpha[rr];
    // ---- P -> LDS bounce (XOR-swizzled) ----
#pragma unroll
    for (int n = 0; n < 4; ++n)
#pragma unroll
      for (int rr = 0; rr < 4; ++rr) {
        int row = g * 4 + rr, col = n * 16 + r16;
        p_lds[w][(row << 6) + ((((col >> 3) ^ (row & 7)) << 3)) + (col & 7)] =
            (bf16)sacc[n][rr];
      }
    asm volatile("s_waitcnt lgkmcnt(0)" ::: "memory");
    // ---- PV from LDS (swizzled reads) ----
    __builtin_amdgcn_s_setprio(1);
#pragma unroll
    for (int kk2 = 0; kk2 < 2; ++kk2) {
      bf16x8 pf = *reinterpret_cast<const bf16x8*>(
          &p_lds[w][(r16 << 6) + (((kk2 * 4 + g) ^ (r16 & 7)) << 3)]);
#pragma unroll
      for (int nc = 0; nc < 8; ++nc) {
        int vr = nc * 16 + r16;
        bf16x8 vf = *reinterpret_cast<const bf16x8*>(
            &Vs[buf][(vr << 6) + (((kk2 * 4 + g) ^ (vr & 7)) << 3)]);
        o[nc] = __builtin_amdgcn_mfma_f32_16x16x32_bf16(pf, vf, o[nc], 0, 0, 0);
      }
    }
    __builtin_amdgcn_s_setprio(0);
    __syncthreads();  // drains vmcnt (next tile ready) + all waves done with buf
    buf ^= 1;
  }

  if (s < 0) {
    // direct path: normalize, write bf16 [t][h*C+c]
#pragma unroll
    for (int rr = 0; rr < 4; ++rr) {
      float inv = 1.0f / lrow[rr];
      int trow = qr0 + g * 4 + rr;
#pragma unroll
      for (int nc = 0; nc < 8; ++nc)
        AO[(size_t)trow * D_DIM + h * C_DIM + nc * 16 + r16] = (bf16)(o[nc][rr] * inv);
    }
  } else {
    // partial path: write unnormalized U (f32) + (m,l)
    const int qi = qb - 16;
    const size_t ubase = ((size_t)(h * 16 + qi) * 2 + s) * (64 * 128);
    const size_t mlbase = (size_t)(h * 16 + qi) * 256 + s * 128;
#pragma unroll
    for (int rr = 0; rr < 4; ++rr) {
      int row = w * 16 + g * 4 + rr;
#pragma unroll
      for (int nc = 0; nc < 8; ++nc)
        U[ubase + (size_t)row * 128 + nc * 16 + r16] = o[nc][rr];
      if (r16 == 0) {
        ML[mlbase + row] = mrow[rr];
        ML[mlbase + 64 + row] = lrow[rr];
      }
    }
  }
}

// ---------------- combine: merge the two KV-split partials for qb>=16 ----------------
__global__ __launch_bounds__(256) void attn_combine(
    const float* __restrict__ U, const float* __restrict__ ML, bf16* __restrict__ AO)
{
  int idx = blockIdx.x * 256 + threadIdx.x;   // 524288 threads, 4 cols each
  int c4 = (idx & 31) * 4;
  int r = idx >> 5;          // row id: 16384
  int trow = r & 63;
  int qi = (r >> 6) & 15;
  int h = r >> 10;

  size_t mlbase = (size_t)(h * 16 + qi) * 256;
  float m0 = ML[mlbase + trow],       l0 = ML[mlbase + 64 + trow];
  float m1 = ML[mlbase + 128 + trow], l1 = ML[mlbase + 192 + trow];
  float m = fmaxf(m0, m1);
  float a0 = __expf(m0 - m), a1 = __expf(m1 - m);
  float inv = 1.0f / (l0 * a0 + l1 * a1);

  size_t t0 = ((size_t)(h * 16 + qi) * 2) * (64 * 128) + (size_t)trow * 128 + c4;
  float4 u0 = *reinterpret_cast<const float4*>(U + t0);
  float4 u1 = *reinterpret_cast<const float4*>(U + t0 + 64 * 128);
  int t = 1024 + qi * 64 + trow;
  bf16x4 ob;
  ob[0] = (bf16)((u0.x * a0 + u1.x * a1) * inv);
  ob[1] = (bf16)((u0.y * a0 + u1.y * a1) * inv);
  ob[2] = (bf16)((u0.z * a0 + u1.z * a1) * inv);
  ob[3] = (bf16)((u0.w * a0 + u1.w * a1) * inv);
  *reinterpret_cast<bf16x4*>(&AO[(size_t)t * D_DIM + h * C_DIM + c4]) = ob;
}

// ---------------- launch ----------------
extern "C" void kernel_launch(void* const* d_in, const int* in_sizes, int n_in,
                              void* d_out, int out_size, void* d_ws, size_t ws_size,
                              hipStream_t stream)
{
  const float* x      = (const float*)d_in[0];
  const float* W_attn = (const float*)d_in[1];
  const float* b_attn = (const float*)d_in[2];
  const float* W_proj = (const float*)d_in[3];
  const float* b_proj = (const float*)d_in[4];
  const float* q_ln_w = (const float*)d_in[5];
  const float* k_ln_w = (const float*)d_in[6];

  char* ws = (char*)d_ws;
  bf16*  x_bf  = (bf16*)(ws + 0);           //  8 MB
  bf16*  wa_bf = (bf16*)(ws + 8388608);     // 24 MB
  bf16*  wp_bf = (bf16*)(ws + 33554432);    //  8 MB
  float* qkv   = (float*)(ws + 41943040);   // 48 MB (dead after ln_rope/v_transpose)
  bf16*  q_bf  = (bf16*)(ws + 92274688);    //  8 MB
  bf16*  k_bf  = (bf16*)(ws + 100663296);   //  8 MB
  bf16*  vt    = (bf16*)(ws + 109051904);   //  8 MB
  bf16*  ao    = (bf16*)(ws + 117440512);   //  8 MB (total 120 MB)
  // U/ML alias the qkv region (qkv fully consumed before attn runs)
  float* U  = (float*)(ws + 41943040);      // 16 MB
  float* ML = (float*)(ws + 58720256);      // 256 KB

  cvt_f32_to_bf16<<<2048, 256, 0, stream>>>(x,      x_bf,  T_DIM * D_DIM / 4);
  cvt_f32_to_bf16<<<2048, 256, 0, stream>>>(W_attn, wa_bf, 3 * D_DIM * D_DIM / 4);
  cvt_f32_to_bf16<<<2048, 256, 0, stream>>>(W_proj, wp_bf, D_DIM * D_DIM / 4);

  gemm_bt_bias<<<dim3(3 * D_DIM / 128, T_DIM / 128), 256, 0, stream>>>(
      x_bf, wa_bf, b_attn, qkv, T_DIM, 3 * D_DIM, D_DIM);

  ln_rope_kernel<<<(H_DIM * T_DIM) / 4, 256, 0, stream>>>(qkv, q_ln_w, k_ln_w, q_bf, k_bf);
  v_transpose_kernel<<<dim3(T_DIM / 32, C_DIM / 32, H_DIM), dim3(32, 8), 0, stream>>>(qkv, vt);

  attn_kernel<<<dim3(48, H_DIM), 256, 0, stream>>>(q_bf, k_bf, vt, ao, U, ML);
  attn_combine<<<2048, 256, 0, stream>>>(U, ML, ao);

  gemm_bt_bias<<<dim3(D_DIM / 128, T_DIM / 128), 256, 0, stream>>>(
      ao, wp_bf, b_proj, (float*)d_out, T_DIM, D_DIM, D_DIM);
}

// Round 4
// 208.709 us; speedup vs baseline: 1.1561x; 1.1561x over previous
//
#include <hip/hip_runtime.h>
#include <hip/hip_bf16.h>
#include <math.h>

#define T_DIM 2048
#define D_DIM 2048
#define H_DIM 16
#define C_DIM 128

typedef __bf16 bf16;
typedef __attribute__((ext_vector_type(8))) __bf16 bf16x8;
typedef __attribute__((ext_vector_type(4))) __bf16 bf16x4;
typedef __attribute__((ext_vector_type(2))) __bf16 bf16x2;
typedef __attribute__((ext_vector_type(4))) float f32x4;

__device__ __forceinline__ void gload_lds16(const void* g, void* l) {
  __builtin_amdgcn_global_load_lds((__attribute__((address_space(1))) void*)g,
                                   (__attribute__((address_space(3))) void*)l,
                                   16, 0, 0);
}

// ---------------- fp32 -> bf16 conversion (vectorized) ----------------
__global__ __launch_bounds__(256) void cvt_f32_to_bf16(
    const float* __restrict__ src, bf16* __restrict__ dst, int n4)
{
  int i = blockIdx.x * blockDim.x + threadIdx.x;
  int stride = gridDim.x * blockDim.x;
  for (; i < n4; i += stride) {
    float4 v = reinterpret_cast<const float4*>(src)[i];
    bf16x4 o;
    o[0] = (bf16)v.x; o[1] = (bf16)v.y; o[2] = (bf16)v.z; o[3] = (bf16)v.w;
    reinterpret_cast<bf16x4*>(dst)[i] = o;
  }
}

// ---------------- GEMM: C(MxN) = A(MxK) @ B(NxK)^T + bias, fp32 out ----------------
__global__ __launch_bounds__(256) void gemm_bt_bias(
    const bf16* __restrict__ A, const bf16* __restrict__ B,
    const float* __restrict__ bias, float* __restrict__ C,
    int M, int N, int K)
{
  __shared__ __align__(16) bf16 As[128 * 32];
  __shared__ __align__(16) bf16 Bs[128 * 32];
  const int tid = threadIdx.x;
  const int lane = tid & 63;
  const int w = tid >> 6;
  const int wm = (w >> 1) * 64, wn = (w & 1) * 64;
  const int g = lane >> 4;
  const int r16 = lane & 15;
  const int bm = blockIdx.y, bn = blockIdx.x;

  f32x4 acc[4][4] = {};

  const size_t Abase = (size_t)(bm * 128) * K;
  const size_t Bbase = (size_t)(bn * 128) * K;

  for (int k0 = 0; k0 < K; k0 += 32) {
#pragma unroll
    for (int c = 0; c < 2; ++c) {
      int e = c * 256 + tid;
      int row = e >> 2, col = (e & 3) * 8;
      gload_lds16(A + Abase + (size_t)row * K + k0 + col, (char*)As + (size_t)e * 16);
      gload_lds16(B + Bbase + (size_t)row * K + k0 + col, (char*)Bs + (size_t)e * 16);
    }
    __syncthreads();
    bf16x8 a[4], b[4];
#pragma unroll
    for (int m = 0; m < 4; ++m)
      a[m] = *reinterpret_cast<const bf16x8*>(&As[(wm + m * 16 + r16) * 32 + g * 8]);
#pragma unroll
    for (int n = 0; n < 4; ++n)
      b[n] = *reinterpret_cast<const bf16x8*>(&Bs[(wn + n * 16 + r16) * 32 + g * 8]);
#pragma unroll
    for (int m = 0; m < 4; ++m)
#pragma unroll
      for (int n = 0; n < 4; ++n)
        acc[m][n] = __builtin_amdgcn_mfma_f32_16x16x32_bf16(a[m], b[n], acc[m][n], 0, 0, 0);
    __syncthreads();
  }

#pragma unroll
  for (int m = 0; m < 4; ++m) {
    int row0 = bm * 128 + wm + m * 16 + g * 4;
#pragma unroll
    for (int n = 0; n < 4; ++n) {
      int col = bn * 128 + wn + n * 16 + r16;
      float bv = bias[col];
#pragma unroll
      for (int rr = 0; rr < 4; ++rr)
        C[(size_t)(row0 + rr) * N + col] = acc[m][n][rr] + bv;
    }
  }
}

// ---------------- LayerNorm + RoPE + pack q/k to bf16 [h][t][c] ----------------
__global__ __launch_bounds__(256) void ln_rope_kernel(
    const float* __restrict__ qkv, const float* __restrict__ qw,
    const float* __restrict__ kw, bf16* __restrict__ qo, bf16* __restrict__ ko)
{
  const int tid = threadIdx.x;
  const int lane = tid & 63;
  const int wid = blockIdx.x * 4 + (tid >> 6);
  const int h = wid >> 11;          // / T
  const int t = wid & (T_DIM - 1);
  const int c0 = lane * 2;

  float inv_freq = exp2f(-13.287712379549449f * (float)c0 * (1.0f / 128.0f));
  float fr = (float)t * inv_freq;
  float sn = sinf(fr), cs = cosf(fr);
  const float scaleq = 0.08838834764831845f; // 1/sqrt(128)

#pragma unroll
  for (int which = 0; which < 2; ++which) {
    const float* base = qkv + (size_t)t * (3 * D_DIM) + which * D_DIM + h * C_DIM;
    float2 v = *reinterpret_cast<const float2*>(base + c0);
    float s = v.x + v.y;
#pragma unroll
    for (int m = 32; m; m >>= 1) s += __shfl_xor(s, m);
    float mu = s * (1.0f / 128.0f);
    float d0 = v.x - mu, d1 = v.y - mu;
    float ss = d0 * d0 + d1 * d1;
#pragma unroll
    for (int m = 32; m; m >>= 1) ss += __shfl_xor(ss, m);
    float rstd = rsqrtf(ss * (1.0f / 128.0f) + 1e-6f);
    const float* wgt = which ? kw : qw;
    float x0 = d0 * rstd * wgt[c0], x1 = d1 * rstd * wgt[c0 + 1];
    float o0 = x0 * cs - x1 * sn;
    float o1 = x1 * cs + x0 * sn;
    if (!which) { o0 *= scaleq; o1 *= scaleq; }
    bf16* out = (which ? ko : qo) + ((size_t)h * T_DIM + t) * C_DIM + c0;
    bf16x2 ob; ob[0] = (bf16)o0; ob[1] = (bf16)o1;
    *reinterpret_cast<bf16x2*>(out) = ob;
  }
}

// ---------------- V transpose: qkv v-part (t,c) -> vt bf16 [h][c][t] ----------------
__global__ __launch_bounds__(256) void v_transpose_kernel(
    const float* __restrict__ qkv, bf16* __restrict__ vt)
{
  __shared__ bf16 tile[32][33];
  const int h = blockIdx.z;
  const int t0 = blockIdx.x * 32, c0 = blockIdx.y * 32;
  const int tx = threadIdx.x, ty = threadIdx.y;
#pragma unroll
  for (int i = 0; i < 4; ++i) {
    int t = t0 + ty + i * 8;
    tile[ty + i * 8][tx] =
        (bf16)qkv[(size_t)t * (3 * D_DIM) + 2 * D_DIM + h * C_DIM + c0 + tx];
  }
  __syncthreads();
#pragma unroll
  for (int i = 0; i < 4; ++i) {
    int c = c0 + ty + i * 8;
    vt[((size_t)h * C_DIM + c) * T_DIM + t0 + tx] = tile[tx][ty + i * 8];
  }
}

// ---------------- Flash attention (causal), swapped-QK^T lane-local softmax ----------
// Each lane owns ONE q-row (q = qr0 + r16): mfma(kf,qf) -> S^T, so the row-reduce is
// an in-register tree + 2 shfl_xor (16,32). PV is swapped too: mfma(vf,pf) -> O^T.
// KVBLK=32, K/V double-buffered in LDS (36 KB total -> 4 blocks/CU).
// Blocks: x in [0,48), y = head.
//   b <  32: qb = 16 + (b>>1), sp = b&1: KV 32-tiles [sp?32:0, sp?2qb+2:32) -> U/ML
//   b >= 32: qb = 47 - b, full range [0, 2qb+2) -> direct AO
__global__ __launch_bounds__(256, 4) void attn_kernel(
    const bf16* __restrict__ Q, const bf16* __restrict__ K,
    const bf16* __restrict__ VT, bf16* __restrict__ AO,
    float* __restrict__ U, float* __restrict__ ML)
{
  __shared__ __align__(16) bf16 Ks[2][32 * 128];   // 16 KB
  __shared__ __align__(16) bf16 Vs[2][128 * 32];   // 16 KB
  __shared__ __align__(16) bf16 p_lds[4][16 * 32]; //  4 KB
  const int tid = threadIdx.x;
  const int lane = tid & 63;
  const int w = tid >> 6;
  const int g = lane >> 4, r16 = lane & 15;
  const int h = blockIdx.y;
  const int b = blockIdx.x;

  int qb, kb0, kb1, sp;
  if (b < 32) { qb = 16 + (b >> 1); sp = b & 1; kb0 = sp * 32; kb1 = sp ? (2 * qb + 2) : 32; }
  else        { qb = 47 - b;        sp = -1;    kb0 = 0;       kb1 = 2 * qb + 2; }
  const int qr0 = qb * 64 + w * 16;
  const int qrow = qr0 + r16;   // this lane's q-row

  const bf16* Qh = Q + (size_t)h * T_DIM * C_DIM;
  const bf16* Kh = K + (size_t)h * T_DIM * C_DIM;
  const bf16* Vh = VT + (size_t)h * C_DIM * T_DIM;

  bf16x8 qf[4];
#pragma unroll
  for (int kk = 0; kk < 4; ++kk)
    qf[kk] = *reinterpret_cast<const bf16x8*>(
        &Qh[(size_t)qrow * C_DIM + kk * 32 + g * 8]);

  float mrow = -INFINITY, lrow = 0.f;
  f32x4 o[8] = {};

  // stage K(32x128) + V(128x32) 32-tile kb into buffer; 4 x 16B per thread.
  auto stage = [&](int bb, int kb) {
    const bf16* Kt = Kh + (size_t)(kb * 32) * C_DIM;
    const bf16* Vt = Vh + kb * 32;
#pragma unroll
    for (int i = 0; i < 2; ++i) {
      int e = i * 256 + tid;                       // 0..511
      int r = e >> 4, p = e & 15, j = p ^ (r & 7); // K: 32 rows x 16 chunks
      gload_lds16(Kt + r * C_DIM + j * 8, (char*)&Ks[bb][0] + (size_t)e * 16);
    }
#pragma unroll
    for (int i = 0; i < 2; ++i) {
      int e = i * 256 + tid;
      int r = e >> 2, p = e & 3, j = p ^ ((r >> 1) & 3); // V: 128 rows x 4 chunks
      gload_lds16(Vt + (size_t)r * T_DIM + j * 8, (char*)&Vs[bb][0] + (size_t)e * 16);
    }
  };

  stage(0, kb0);
  __syncthreads();  // drains vmcnt: first tile ready
  int buf = 0;

  for (int kb = kb0; kb < kb1; ++kb) {
    if (kb + 1 < kb1) stage(buf ^ 1, kb + 1);  // latency hides under compute

    // ---- QK^T swapped: sacc[n] = S^T (key rows, q cols) ----
    f32x4 sacc[2] = {};
    __builtin_amdgcn_s_setprio(1);
#pragma unroll
    for (int n = 0; n < 2; ++n) {
      int kr = n * 16 + r16;
      const bf16* kbase = &Ks[buf][kr << 7];
#pragma unroll
      for (int kk = 0; kk < 4; ++kk) {
        bf16x8 kf = *reinterpret_cast<const bf16x8*>(
            kbase + (((kk * 4 + g) ^ (kr & 7)) << 3));
        sacc[n] = __builtin_amdgcn_mfma_f32_16x16x32_bf16(kf, qf[kk], sacc[n], 0, 0, 0);
      }
    }
    __builtin_amdgcn_s_setprio(0);
    // causal mask (per-lane row; skip when whole tile is past-causal for wave)
    if (kb * 32 + 31 > qr0) {
#pragma unroll
      for (int n = 0; n < 2; ++n)
#pragma unroll
        for (int rr = 0; rr < 4; ++rr)
          if (kb * 32 + n * 16 + g * 4 + rr > qrow) sacc[n][rr] = -3.0e38f;
    }
    // ---- lane-local online softmax ----
    float mx = fmaxf(fmaxf(fmaxf(sacc[0][0], sacc[0][1]), fmaxf(sacc[0][2], sacc[0][3])),
                     fmaxf(fmaxf(sacc[1][0], sacc[1][1]), fmaxf(sacc[1][2], sacc[1][3])));
    mx = fmaxf(mx, __shfl_xor(mx, 16));
    mx = fmaxf(mx, __shfl_xor(mx, 32));
    float alpha = 1.0f;
    bool need = __any(mx > mrow + 8.0f);  // T13 defer-rescale, wave-uniform
    if (need) {
      float mnew = fmaxf(mrow, mx);
      alpha = __expf(mrow - mnew);
      mrow = mnew;
    }
    float ps = 0.f;
#pragma unroll
    for (int n = 0; n < 2; ++n)
#pragma unroll
      for (int rr = 0; rr < 4; ++rr) {
        float p = __expf(sacc[n][rr] - mrow);
        sacc[n][rr] = p;
        ps += p;
      }
    ps += __shfl_xor(ps, 16);
    ps += __shfl_xor(ps, 32);
    lrow = lrow * alpha + ps;
    if (need) {
#pragma unroll
      for (int nc = 0; nc < 8; ++nc)
#pragma unroll
        for (int rr = 0; rr < 4; ++rr)
          o[nc][rr] *= alpha;
    }
    // ---- P -> p_lds: row q=r16, col key; 2 x ds_write_b64, 2-way max ----
    {
      bf16* prow = &p_lds[w][r16 << 5];
      const int ssw = (r16 >> 1) & 3;
#pragma unroll
      for (int n = 0; n < 2; ++n) {
        bf16x4 pk;
        pk[0] = (bf16)sacc[n][0]; pk[1] = (bf16)sacc[n][1];
        pk[2] = (bf16)sacc[n][2]; pk[3] = (bf16)sacc[n][3];
        int c8 = 2 * n + (g >> 1);
        *reinterpret_cast<bf16x4*>(prow + (((c8 ^ ssw) << 3) | ((g & 1) << 2))) = pk;
      }
    }
    asm volatile("s_waitcnt lgkmcnt(0)" ::: "memory");
    // ---- PV swapped: o[nc] += V^T-tile x P^T ----
    __builtin_amdgcn_s_setprio(1);
    bf16x8 pf = *reinterpret_cast<const bf16x8*>(
        &p_lds[w][(r16 << 5) + ((g ^ ((r16 >> 1) & 3)) << 3)]);
#pragma unroll
    for (int nc = 0; nc < 8; ++nc) {
      int vr = nc * 16 + r16;
      bf16x8 vf = *reinterpret_cast<const bf16x8*>(
          &Vs[buf][(vr << 5) + ((g ^ ((vr >> 1) & 3)) << 3)]);
      o[nc] = __builtin_amdgcn_mfma_f32_16x16x32_bf16(vf, pf, o[nc], 0, 0, 0);
    }
    __builtin_amdgcn_s_setprio(0);
    __syncthreads();  // drains vmcnt (next tile ready) + all waves done with buf
    buf ^= 1;
  }

  if (sp < 0) {
    // direct path: normalize; lane owns row qrow, cols nc*16 + g*4 .. +3
    float inv = 1.0f / lrow;
    bf16* arow = &AO[(size_t)qrow * D_DIM + h * C_DIM + (g << 2)];
#pragma unroll
    for (int nc = 0; nc < 8; ++nc) {
      bf16x4 ob;
      ob[0] = (bf16)(o[nc][0] * inv); ob[1] = (bf16)(o[nc][1] * inv);
      ob[2] = (bf16)(o[nc][2] * inv); ob[3] = (bf16)(o[nc][3] * inv);
      *reinterpret_cast<bf16x4*>(arow + nc * 16) = ob;
    }
  } else {
    // partial path: unnormalized U (f32) + (m,l)
    const int qi = qb - 16;
    const size_t ubase = ((size_t)(h * 16 + qi) * 2 + sp) * (64 * 128);
    const size_t mlbase = (size_t)(h * 16 + qi) * 256 + sp * 128;
    const int row = w * 16 + r16;
    float* urow = &U[ubase + (size_t)row * 128 + (g << 2)];
#pragma unroll
    for (int nc = 0; nc < 8; ++nc)
      *reinterpret_cast<f32x4*>(urow + nc * 16) = o[nc];
    if (g == 0) {
      ML[mlbase + row] = mrow;
      ML[mlbase + 64 + row] = lrow;
    }
  }
}

// ---------------- combine: merge the two KV-split partials for qb>=16 ----------------
__global__ __launch_bounds__(256) void attn_combine(
    const float* __restrict__ U, const float* __restrict__ ML, bf16* __restrict__ AO)
{
  int idx = blockIdx.x * 256 + threadIdx.x;   // 524288 threads, 4 cols each
  int c4 = (idx & 31) * 4;
  int r = idx >> 5;          // row id: 16384
  int trow = r & 63;
  int qi = (r >> 6) & 15;
  int h = r >> 10;

  size_t mlbase = (size_t)(h * 16 + qi) * 256;
  float m0 = ML[mlbase + trow],       l0 = ML[mlbase + 64 + trow];
  float m1 = ML[mlbase + 128 + trow], l1 = ML[mlbase + 192 + trow];
  float m = fmaxf(m0, m1);
  float a0 = __expf(m0 - m), a1 = __expf(m1 - m);
  float inv = 1.0f / (l0 * a0 + l1 * a1);

  size_t t0 = ((size_t)(h * 16 + qi) * 2) * (64 * 128) + (size_t)trow * 128 + c4;
  float4 u0 = *reinterpret_cast<const float4*>(U + t0);
  float4 u1 = *reinterpret_cast<const float4*>(U + t0 + 64 * 128);
  int t = 1024 + qi * 64 + trow;
  bf16x4 ob;
  ob[0] = (bf16)((u0.x * a0 + u1.x * a1) * inv);
  ob[1] = (bf16)((u0.y * a0 + u1.y * a1) * inv);
  ob[2] = (bf16)((u0.z * a0 + u1.z * a1) * inv);
  ob[3] = (bf16)((u0.w * a0 + u1.w * a1) * inv);
  *reinterpret_cast<bf16x4*>(&AO[(size_t)t * D_DIM + h * C_DIM + c4]) = ob;
}

// ---------------- launch ----------------
extern "C" void kernel_launch(void* const* d_in, const int* in_sizes, int n_in,
                              void* d_out, int out_size, void* d_ws, size_t ws_size,
                              hipStream_t stream)
{
  const float* x      = (const float*)d_in[0];
  const float* W_attn = (const float*)d_in[1];
  const float* b_attn = (const float*)d_in[2];
  const float* W_proj = (const float*)d_in[3];
  const float* b_proj = (const float*)d_in[4];
  const float* q_ln_w = (const float*)d_in[5];
  const float* k_ln_w = (const float*)d_in[6];

  char* ws = (char*)d_ws;
  bf16*  x_bf  = (bf16*)(ws + 0);           //  8 MB
  bf16*  wa_bf = (bf16*)(ws + 8388608);     // 24 MB
  bf16*  wp_bf = (bf16*)(ws + 33554432);    //  8 MB
  float* qkv   = (float*)(ws + 41943040);   // 48 MB (dead after ln_rope/v_transpose)
  bf16*  q_bf  = (bf16*)(ws + 92274688);    //  8 MB
  bf16*  k_bf  = (bf16*)(ws + 100663296);   //  8 MB
  bf16*  vt    = (bf16*)(ws + 109051904);   //  8 MB
  bf16*  ao    = (bf16*)(ws + 117440512);   //  8 MB (total 120 MB)
  // U/ML alias the qkv region (qkv fully consumed before attn runs)
  float* U  = (float*)(ws + 41943040);      // 16 MB
  float* ML = (float*)(ws + 58720256);      // 256 KB

  cvt_f32_to_bf16<<<2048, 256, 0, stream>>>(x,      x_bf,  T_DIM * D_DIM / 4);
  cvt_f32_to_bf16<<<2048, 256, 0, stream>>>(W_attn, wa_bf, 3 * D_DIM * D_DIM / 4);
  cvt_f32_to_bf16<<<2048, 256, 0, stream>>>(W_proj, wp_bf, D_DIM * D_DIM / 4);

  gemm_bt_bias<<<dim3(3 * D_DIM / 128, T_DIM / 128), 256, 0, stream>>>(
      x_bf, wa_bf, b_attn, qkv, T_DIM, 3 * D_DIM, D_DIM);

  ln_rope_kernel<<<(H_DIM * T_DIM) / 4, 256, 0, stream>>>(qkv, q_ln_w, k_ln_w, q_bf, k_bf);
  v_transpose_kernel<<<dim3(T_DIM / 32, C_DIM / 32, H_DIM), dim3(32, 8), 0, stream>>>(qkv, vt);

  attn_kernel<<<dim3(48, H_DIM), 256, 0, stream>>>(q_bf, k_bf, vt, ao, U, ML);
  attn_combine<<<2048, 256, 0, stream>>>(U, ML, ao);

  gemm_bt_bias<<<dim3(D_DIM / 128, T_DIM / 128), 256, 0, stream>>>(
      ao, wp_bf, b_proj, (float*)d_out, T_DIM, D_DIM, D_DIM);
}

// Round 5
// 202.221 us; speedup vs baseline: 1.1932x; 1.0321x over previous
//
#include <hip/hip_runtime.h>
#include <hip/hip_bf16.h>
#include <math.h>

#define T_DIM 2048
#define D_DIM 2048
#define H_DIM 16
#define C_DIM 128

typedef __bf16 bf16;
typedef __attribute__((ext_vector_type(8))) __bf16 bf16x8;
typedef __attribute__((ext_vector_type(4))) __bf16 bf16x4;
typedef __attribute__((ext_vector_type(2))) __bf16 bf16x2;
typedef __attribute__((ext_vector_type(4))) float f32x4;

__device__ __forceinline__ void gload_lds16(const void* g, void* l) {
  __builtin_amdgcn_global_load_lds((__attribute__((address_space(1))) void*)g,
                                   (__attribute__((address_space(3))) void*)l,
                                   16, 0, 0);
}

// ---------------- fp32 -> bf16 conversion (vectorized) ----------------
__global__ __launch_bounds__(256) void cvt_f32_to_bf16(
    const float* __restrict__ src, bf16* __restrict__ dst, int n4)
{
  int i = blockIdx.x * blockDim.x + threadIdx.x;
  int stride = gridDim.x * blockDim.x;
  for (; i < n4; i += stride) {
    float4 v = reinterpret_cast<const float4*>(src)[i];
    bf16x4 o;
    o[0] = (bf16)v.x; o[1] = (bf16)v.y; o[2] = (bf16)v.z; o[3] = (bf16)v.w;
    reinterpret_cast<bf16x4*>(dst)[i] = o;
  }
}

// ============ 256x256 8-phase GEMM: C = A(MxK) @ B(NxK)^T + bias (fp32 out) ============
// 8 waves (512 thr), BK=64, LDS 128 KB = 2 K-tile dbuf. Phases = block C-quadrants in
// Gray order (0,0),(0,1),(1,1),(1,0); one half-tile (128 rows x 64 K) staged per phase
// via global_load_lds(16B) with chunk-XOR swizzle (pre-swizzled source, swizzled read).
// Counted vmcnt(4): each staged half is consumed >=3 phases after issue; never drains.
__global__ __launch_bounds__(512, 2) void gemm256_bt_bias(
    const bf16* __restrict__ A, const bf16* __restrict__ B,
    const float* __restrict__ bias, float* __restrict__ C,
    int M, int N, int K)
{
  __shared__ __align__(16) bf16 Asl[2][256 * 64];  // 64 KB
  __shared__ __align__(16) bf16 Bsl[2][256 * 64];  // 64 KB
  const int tid = threadIdx.x;
  const int lane = tid & 63;
  const int wv = tid >> 6;          // 0..7
  const int g = lane >> 4, r16 = lane & 15;

  // XCD swizzle (gridDim.x % 8 == 0): each XCD gets a contiguous chunk (one A-panel row)
  int bid = blockIdx.x;
  int bid2 = (bid & 7) * (gridDim.x >> 3) + (bid >> 3);
  const int ntn = N >> 8;
  const int bn = bid2 % ntn, bm = bid2 / ntn;

  const size_t Abase = (size_t)(bm * 256) * K;
  const size_t Bbase = (size_t)(bn * 256) * K;

  f32x4 acc[2][2][2][4] = {};   // [qr][qc][R][F]
  bf16x8 a[2][2], b[4][2];      // [R][ks], [F][ks]

  // stage one half-tile (128 rows x 64 K = 16 KB): 2 x 16B per thread, lane-linear LDS
  // dest, inverse-swizzled global source (chunk j = p ^ (r&7)).
  auto stageA = [&](int bb, int ha, int t) {
#pragma unroll
    for (int i = 0; i < 2; ++i) {
      int c = i * 512 + tid;                    // 0..1023 chunks
      int r = c >> 3, p = c & 7, j = p ^ (r & 7);
      gload_lds16(A + Abase + (size_t)(ha * 128 + r) * K + t * 64 + j * 8,
                  (char*)&Asl[bb][0] + ha * 16384 + (size_t)c * 16);
    }
  };
  auto stageB = [&](int bb, int hb, int t) {
#pragma unroll
    for (int i = 0; i < 2; ++i) {
      int c = i * 512 + tid;
      int r = c >> 3, p = c & 7, j = p ^ (r & 7);
      gload_lds16(B + Bbase + (size_t)(hb * 128 + r) * K + t * 64 + j * 8,
                  (char*)&Bsl[bb][0] + hb * 16384 + (size_t)c * 16);
    }
  };
  auto readA = [&](int bufi, int QR) {
#pragma unroll
    for (int R = 0; R < 2; ++R) {
      int ar = QR * 128 + (wv >> 1) * 32 + R * 16 + r16;
#pragma unroll
      for (int ks = 0; ks < 2; ++ks)
        a[R][ks] = *reinterpret_cast<const bf16x8*>(
            &Asl[bufi][ar * 64 + (((ks * 4 + g) ^ (ar & 7)) << 3)]);
    }
  };
  auto readB = [&](int bufi, int QC) {
#pragma unroll
    for (int F = 0; F < 4; ++F) {
      int br = QC * 128 + (wv & 1) * 64 + F * 16 + r16;
#pragma unroll
      for (int ks = 0; ks < 2; ++ks)
        b[F][ks] = *reinterpret_cast<const bf16x8*>(
            &Bsl[bufi][br * 64 + (((ks * 4 + g) ^ (br & 7)) << 3)]);
    }
  };
  auto mfma16 = [&](f32x4 (&c2)[2][4]) {
    __builtin_amdgcn_s_setprio(1);
#pragma unroll
    for (int ks = 0; ks < 2; ++ks)
#pragma unroll
      for (int R = 0; R < 2; ++R)
#pragma unroll
        for (int F = 0; F < 4; ++F)
          c2[R][F] = __builtin_amdgcn_mfma_f32_16x16x32_bf16(a[R][ks], b[F][ks], c2[R][F], 0, 0, 0);
    __builtin_amdgcn_s_setprio(0);
  };

#define MIDSYNC(VM)                                               \
  asm volatile("s_waitcnt vmcnt(" #VM ")" ::: "memory");          \
  __builtin_amdgcn_s_barrier();                                   \
  asm volatile("s_waitcnt lgkmcnt(0)" ::: "memory");              \
  __builtin_amdgcn_sched_barrier(0);

  // prologue: K-tile 0, halves in order A0,B0,B1,A1 (8 loads/thread)
  stageA(0, 0, 0); stageB(0, 0, 0); stageB(0, 1, 0); stageA(0, 1, 0);
  asm volatile("s_waitcnt vmcnt(4)" ::: "memory");  // A0,B0 landed
  __builtin_amdgcn_s_barrier();

  const int NT = K >> 6;
  for (int t = 0; t < NT; ++t) {
    const int cb = t & 1, nb = cb ^ 1;
    const bool pf = (t + 1 < NT);
    // P1: quadrant (0,0) — reads A0,B0 of t; stages A0(t+1)
    readA(cb, 0);
    readB(cb, 0);
    if (pf) stageA(nb, 0, t + 1);
    MIDSYNC(4)                     // guarantees B1(t) landed (needed at P2)
    mfma16(acc[0][0]);
    __builtin_amdgcn_s_barrier();
    // P2: quadrant (0,1) — reads B1 of t (A reused); stages B0(t+1)
    readB(cb, 1);
    if (pf) stageB(nb, 0, t + 1);
    MIDSYNC(4)                     // guarantees A1(t) landed (needed at P3)
    mfma16(acc[0][1]);
    __builtin_amdgcn_s_barrier();
    // P3: quadrant (1,1) — reads A1 of t (B reused); stages B1(t+1)
    readA(cb, 1);
    if (pf) stageB(nb, 1, t + 1);
    __builtin_amdgcn_s_barrier();
    asm volatile("s_waitcnt lgkmcnt(0)" ::: "memory");
    __builtin_amdgcn_sched_barrier(0);
    mfma16(acc[1][1]);
    __builtin_amdgcn_s_barrier();
    // P4: quadrant (1,0) — re-reads B0 of t; stages A1(t+1)
    readB(cb, 0);
    if (pf) stageA(nb, 1, t + 1);
    MIDSYNC(4)                     // guarantees A0(t+1),B0(t+1) landed (needed at next P1)
    mfma16(acc[1][0]);
    __builtin_amdgcn_s_barrier();
  }
#undef MIDSYNC

  // epilogue: bias + fp32 store
#pragma unroll
  for (int qr = 0; qr < 2; ++qr)
#pragma unroll
    for (int qc = 0; qc < 2; ++qc)
#pragma unroll
      for (int R = 0; R < 2; ++R)
#pragma unroll
        for (int F = 0; F < 4; ++F) {
          int row0 = bm * 256 + qr * 128 + (wv >> 1) * 32 + R * 16 + g * 4;
          int col  = bn * 256 + qc * 128 + (wv & 1) * 64 + F * 16 + r16;
          float bv = bias[col];
#pragma unroll
          for (int rr = 0; rr < 4; ++rr)
            C[(size_t)(row0 + rr) * N + col] = acc[qr][qc][R][F][rr] + bv;
        }
}

// ---------------- 128x128 GEMM (2-phase dbuf): C = A @ B^T + bias ----------------
__global__ __launch_bounds__(256) void gemm_bt_bias(
    const bf16* __restrict__ A, const bf16* __restrict__ B,
    const float* __restrict__ bias, float* __restrict__ C,
    int M, int N, int K)
{
  __shared__ __align__(16) bf16 As[2][128 * 32];
  __shared__ __align__(16) bf16 Bs[2][128 * 32];
  const int tid = threadIdx.x;
  const int lane = tid & 63;
  const int w = tid >> 6;
  const int wm = (w >> 1) * 64, wn = (w & 1) * 64;
  const int g = lane >> 4;
  const int r16 = lane & 15;
  const int bm = blockIdx.y, bn = blockIdx.x;

  f32x4 acc[4][4] = {};

  const size_t Abase = (size_t)(bm * 128) * K;
  const size_t Bbase = (size_t)(bn * 128) * K;

  auto stage = [&](int bb, int k0) {
#pragma unroll
    for (int c = 0; c < 2; ++c) {
      int e = c * 256 + tid;
      int row = e >> 2, col = (e & 3) * 8;
      gload_lds16(A + Abase + (size_t)row * K + k0 + col, (char*)&As[bb][0] + (size_t)e * 16);
      gload_lds16(B + Bbase + (size_t)row * K + k0 + col, (char*)&Bs[bb][0] + (size_t)e * 16);
    }
  };

  stage(0, 0);
  __syncthreads();

  for (int k0 = 0; k0 < K; k0 += 32) {
    const int cur = (k0 >> 5) & 1;
    if (k0 + 32 < K) stage(cur ^ 1, k0 + 32);  // overlap next-tile loads with compute
    bf16x8 a[4], b[4];
#pragma unroll
    for (int m = 0; m < 4; ++m)
      a[m] = *reinterpret_cast<const bf16x8*>(&As[cur][(wm + m * 16 + r16) * 32 + g * 8]);
#pragma unroll
    for (int n = 0; n < 4; ++n)
      b[n] = *reinterpret_cast<const bf16x8*>(&Bs[cur][(wn + n * 16 + r16) * 32 + g * 8]);
    __builtin_amdgcn_s_setprio(1);
#pragma unroll
    for (int m = 0; m < 4; ++m)
#pragma unroll
      for (int n = 0; n < 4; ++n)
        acc[m][n] = __builtin_amdgcn_mfma_f32_16x16x32_bf16(a[m], b[n], acc[m][n], 0, 0, 0);
    __builtin_amdgcn_s_setprio(0);
    __syncthreads();  // drains vmcnt (next tile landed) + all waves done with cur
  }

#pragma unroll
  for (int m = 0; m < 4; ++m) {
    int row0 = bm * 128 + wm + m * 16 + g * 4;
#pragma unroll
    for (int n = 0; n < 4; ++n) {
      int col = bn * 128 + wn + n * 16 + r16;
      float bv = bias[col];
#pragma unroll
      for (int rr = 0; rr < 4; ++rr)
        C[(size_t)(row0 + rr) * N + col] = acc[m][n][rr] + bv;
    }
  }
}

// ---------------- LayerNorm + RoPE + pack q/k to bf16 [h][t][c] ----------------
__global__ __launch_bounds__(256) void ln_rope_kernel(
    const float* __restrict__ qkv, const float* __restrict__ qw,
    const float* __restrict__ kw, bf16* __restrict__ qo, bf16* __restrict__ ko)
{
  const int tid = threadIdx.x;
  const int lane = tid & 63;
  const int wid = blockIdx.x * 4 + (tid >> 6);
  const int h = wid >> 11;          // / T
  const int t = wid & (T_DIM - 1);
  const int c0 = lane * 2;

  float inv_freq = exp2f(-13.287712379549449f * (float)c0 * (1.0f / 128.0f));
  float fr = (float)t * inv_freq;
  float sn = sinf(fr), cs = cosf(fr);
  const float scaleq = 0.08838834764831845f; // 1/sqrt(128)

#pragma unroll
  for (int which = 0; which < 2; ++which) {
    const float* base = qkv + (size_t)t * (3 * D_DIM) + which * D_DIM + h * C_DIM;
    float2 v = *reinterpret_cast<const float2*>(base + c0);
    float s = v.x + v.y;
#pragma unroll
    for (int m = 32; m; m >>= 1) s += __shfl_xor(s, m);
    float mu = s * (1.0f / 128.0f);
    float d0 = v.x - mu, d1 = v.y - mu;
    float ss = d0 * d0 + d1 * d1;
#pragma unroll
    for (int m = 32; m; m >>= 1) ss += __shfl_xor(ss, m);
    float rstd = rsqrtf(ss * (1.0f / 128.0f) + 1e-6f);
    const float* wgt = which ? kw : qw;
    float x0 = d0 * rstd * wgt[c0], x1 = d1 * rstd * wgt[c0 + 1];
    float o0 = x0 * cs - x1 * sn;
    float o1 = x1 * cs + x0 * sn;
    if (!which) { o0 *= scaleq; o1 *= scaleq; }
    bf16* out = (which ? ko : qo) + ((size_t)h * T_DIM + t) * C_DIM + c0;
    bf16x2 ob; ob[0] = (bf16)o0; ob[1] = (bf16)o1;
    *reinterpret_cast<bf16x2*>(out) = ob;
  }
}

// ---------------- V transpose: qkv v-part (t,c) -> vt bf16 [h][c][t] ----------------
__global__ __launch_bounds__(256) void v_transpose_kernel(
    const float* __restrict__ qkv, bf16* __restrict__ vt)
{
  __shared__ bf16 tile[32][33];
  const int h = blockIdx.z;
  const int t0 = blockIdx.x * 32, c0 = blockIdx.y * 32;
  const int tx = threadIdx.x, ty = threadIdx.y;
#pragma unroll
  for (int i = 0; i < 4; ++i) {
    int t = t0 + ty + i * 8;
    tile[ty + i * 8][tx] =
        (bf16)qkv[(size_t)t * (3 * D_DIM) + 2 * D_DIM + h * C_DIM + c0 + tx];
  }
  __syncthreads();
#pragma unroll
  for (int i = 0; i < 4; ++i) {
    int c = c0 + ty + i * 8;
    vt[((size_t)h * C_DIM + c) * T_DIM + t0 + tx] = tile[tx][ty + i * 8];
  }
}

// ---------------- Flash attention (causal), swapped-QK^T lane-local softmax ----------
__global__ __launch_bounds__(256, 4) void attn_kernel(
    const bf16* __restrict__ Q, const bf16* __restrict__ K,
    const bf16* __restrict__ VT, bf16* __restrict__ AO,
    float* __restrict__ U, float* __restrict__ ML)
{
  __shared__ __align__(16) bf16 Ks[2][32 * 128];   // 16 KB
  __shared__ __align__(16) bf16 Vs[2][128 * 32];   // 16 KB
  __shared__ __align__(16) bf16 p_lds[4][16 * 32]; //  4 KB
  const int tid = threadIdx.x;
  const int lane = tid & 63;
  const int w = tid >> 6;
  const int g = lane >> 4, r16 = lane & 15;
  const int h = blockIdx.y;
  const int b = blockIdx.x;

  int qb, kb0, kb1, sp;
  if (b < 32) { qb = 16 + (b >> 1); sp = b & 1; kb0 = sp * 32; kb1 = sp ? (2 * qb + 2) : 32; }
  else        { qb = 47 - b;        sp = -1;    kb0 = 0;       kb1 = 2 * qb + 2; }
  const int qr0 = qb * 64 + w * 16;
  const int qrow = qr0 + r16;   // this lane's q-row

  const bf16* Qh = Q + (size_t)h * T_DIM * C_DIM;
  const bf16* Kh = K + (size_t)h * T_DIM * C_DIM;
  const bf16* Vh = VT + (size_t)h * C_DIM * T_DIM;

  bf16x8 qf[4];
#pragma unroll
  for (int kk = 0; kk < 4; ++kk)
    qf[kk] = *reinterpret_cast<const bf16x8*>(
        &Qh[(size_t)qrow * C_DIM + kk * 32 + g * 8]);

  float mrow = -INFINITY, lrow = 0.f;
  f32x4 o[8] = {};

  auto stage = [&](int bb, int kb) {
    const bf16* Kt = Kh + (size_t)(kb * 32) * C_DIM;
    const bf16* Vt = Vh + kb * 32;
#pragma unroll
    for (int i = 0; i < 2; ++i) {
      int e = i * 256 + tid;                       // 0..511
      int r = e >> 4, p = e & 15, j = p ^ (r & 7); // K: 32 rows x 16 chunks
      gload_lds16(Kt + r * C_DIM + j * 8, (char*)&Ks[bb][0] + (size_t)e * 16);
    }
#pragma unroll
    for (int i = 0; i < 2; ++i) {
      int e = i * 256 + tid;
      int r = e >> 2, p = e & 3, j = p ^ ((r >> 1) & 3); // V: 128 rows x 4 chunks
      gload_lds16(Vt + (size_t)r * T_DIM + j * 8, (char*)&Vs[bb][0] + (size_t)e * 16);
    }
  };

  stage(0, kb0);
  __syncthreads();
  int buf = 0;

  for (int kb = kb0; kb < kb1; ++kb) {
    if (kb + 1 < kb1) stage(buf ^ 1, kb + 1);

    f32x4 sacc[2] = {};
    __builtin_amdgcn_s_setprio(1);
#pragma unroll
    for (int n = 0; n < 2; ++n) {
      int kr = n * 16 + r16;
      const bf16* kbase = &Ks[buf][kr << 7];
#pragma unroll
      for (int kk = 0; kk < 4; ++kk) {
        bf16x8 kf = *reinterpret_cast<const bf16x8*>(
            kbase + (((kk * 4 + g) ^ (kr & 7)) << 3));
        sacc[n] = __builtin_amdgcn_mfma_f32_16x16x32_bf16(kf, qf[kk], sacc[n], 0, 0, 0);
      }
    }
    __builtin_amdgcn_s_setprio(0);
    if (kb * 32 + 31 > qr0) {
#pragma unroll
      for (int n = 0; n < 2; ++n)
#pragma unroll
        for (int rr = 0; rr < 4; ++rr)
          if (kb * 32 + n * 16 + g * 4 + rr > qrow) sacc[n][rr] = -3.0e38f;
    }
    float mx = fmaxf(fmaxf(fmaxf(sacc[0][0], sacc[0][1]), fmaxf(sacc[0][2], sacc[0][3])),
                     fmaxf(fmaxf(sacc[1][0], sacc[1][1]), fmaxf(sacc[1][2], sacc[1][3])));
    mx = fmaxf(mx, __shfl_xor(mx, 16));
    mx = fmaxf(mx, __shfl_xor(mx, 32));
    float alpha = 1.0f;
    bool need = __any(mx > mrow + 8.0f);
    if (need) {
      float mnew = fmaxf(mrow, mx);
      alpha = __expf(mrow - mnew);
      mrow = mnew;
    }
    float ps = 0.f;
#pragma unroll
    for (int n = 0; n < 2; ++n)
#pragma unroll
      for (int rr = 0; rr < 4; ++rr) {
        float p = __expf(sacc[n][rr] - mrow);
        sacc[n][rr] = p;
        ps += p;
      }
    ps += __shfl_xor(ps, 16);
    ps += __shfl_xor(ps, 32);
    lrow = lrow * alpha + ps;
    if (need) {
#pragma unroll
      for (int nc = 0; nc < 8; ++nc)
#pragma unroll
        for (int rr = 0; rr < 4; ++rr)
          o[nc][rr] *= alpha;
    }
    {
      bf16* prow = &p_lds[w][r16 << 5];
      const int ssw = (r16 >> 1) & 3;
#pragma unroll
      for (int n = 0; n < 2; ++n) {
        bf16x4 pk;
        pk[0] = (bf16)sacc[n][0]; pk[1] = (bf16)sacc[n][1];
        pk[2] = (bf16)sacc[n][2]; pk[3] = (bf16)sacc[n][3];
        int c8 = 2 * n + (g >> 1);
        *reinterpret_cast<bf16x4*>(prow + (((c8 ^ ssw) << 3) | ((g & 1) << 2))) = pk;
      }
    }
    asm volatile("s_waitcnt lgkmcnt(0)" ::: "memory");
    __builtin_amdgcn_s_setprio(1);
    bf16x8 pf = *reinterpret_cast<const bf16x8*>(
        &p_lds[w][(r16 << 5) + ((g ^ ((r16 >> 1) & 3)) << 3)]);
#pragma unroll
    for (int nc = 0; nc < 8; ++nc) {
      int vr = nc * 16 + r16;
      bf16x8 vf = *reinterpret_cast<const bf16x8*>(
          &Vs[buf][(vr << 5) + ((g ^ ((vr >> 1) & 3)) << 3)]);
      o[nc] = __builtin_amdgcn_mfma_f32_16x16x32_bf16(vf, pf, o[nc], 0, 0, 0);
    }
    __builtin_amdgcn_s_setprio(0);
    __syncthreads();
    buf ^= 1;
  }

  if (sp < 0) {
    float inv = 1.0f / lrow;
    bf16* arow = &AO[(size_t)qrow * D_DIM + h * C_DIM + (g << 2)];
#pragma unroll
    for (int nc = 0; nc < 8; ++nc) {
      bf16x4 ob;
      ob[0] = (bf16)(o[nc][0] * inv); ob[1] = (bf16)(o[nc][1] * inv);
      ob[2] = (bf16)(o[nc][2] * inv); ob[3] = (bf16)(o[nc][3] * inv);
      *reinterpret_cast<bf16x4*>(arow + nc * 16) = ob;
    }
  } else {
    const int qi = qb - 16;
    const size_t ubase = ((size_t)(h * 16 + qi) * 2 + sp) * (64 * 128);
    const size_t mlbase = (size_t)(h * 16 + qi) * 256 + sp * 128;
    const int row = w * 16 + r16;
    float* urow = &U[ubase + (size_t)row * 128 + (g << 2)];
#pragma unroll
    for (int nc = 0; nc < 8; ++nc)
      *reinterpret_cast<f32x4*>(urow + nc * 16) = o[nc];
    if (g == 0) {
      ML[mlbase + row] = mrow;
      ML[mlbase + 64 + row] = lrow;
    }
  }
}

// ---------------- combine: merge the two KV-split partials for qb>=16 ----------------
__global__ __launch_bounds__(256) void attn_combine(
    const float* __restrict__ U, const float* __restrict__ ML, bf16* __restrict__ AO)
{
  int idx = blockIdx.x * 256 + threadIdx.x;
  int c4 = (idx & 31) * 4;
  int r = idx >> 5;
  int trow = r & 63;
  int qi = (r >> 6) & 15;
  int h = r >> 10;

  size_t mlbase = (size_t)(h * 16 + qi) * 256;
  float m0 = ML[mlbase + trow],       l0 = ML[mlbase + 64 + trow];
  float m1 = ML[mlbase + 128 + trow], l1 = ML[mlbase + 192 + trow];
  float m = fmaxf(m0, m1);
  float a0 = __expf(m0 - m), a1 = __expf(m1 - m);
  float inv = 1.0f / (l0 * a0 + l1 * a1);

  size_t t0 = ((size_t)(h * 16 + qi) * 2) * (64 * 128) + (size_t)trow * 128 + c4;
  float4 u0 = *reinterpret_cast<const float4*>(U + t0);
  float4 u1 = *reinterpret_cast<const float4*>(U + t0 + 64 * 128);
  int t = 1024 + qi * 64 + trow;
  bf16x4 ob;
  ob[0] = (bf16)((u0.x * a0 + u1.x * a1) * inv);
  ob[1] = (bf16)((u0.y * a0 + u1.y * a1) * inv);
  ob[2] = (bf16)((u0.z * a0 + u1.z * a1) * inv);
  ob[3] = (bf16)((u0.w * a0 + u1.w * a1) * inv);
  *reinterpret_cast<bf16x4*>(&AO[(size_t)t * D_DIM + h * C_DIM + c4]) = ob;
}

// ---------------- launch ----------------
extern "C" void kernel_launch(void* const* d_in, const int* in_sizes, int n_in,
                              void* d_out, int out_size, void* d_ws, size_t ws_size,
                              hipStream_t stream)
{
  const float* x      = (const float*)d_in[0];
  const float* W_attn = (const float*)d_in[1];
  const float* b_attn = (const float*)d_in[2];
  const float* W_proj = (const float*)d_in[3];
  const float* b_proj = (const float*)d_in[4];
  const float* q_ln_w = (const float*)d_in[5];
  const float* k_ln_w = (const float*)d_in[6];

  char* ws = (char*)d_ws;
  bf16*  x_bf  = (bf16*)(ws + 0);           //  8 MB
  bf16*  wa_bf = (bf16*)(ws + 8388608);     // 24 MB
  bf16*  wp_bf = (bf16*)(ws + 33554432);    //  8 MB
  float* qkv   = (float*)(ws + 41943040);   // 48 MB (dead after ln_rope/v_transpose)
  bf16*  q_bf  = (bf16*)(ws + 92274688);    //  8 MB
  bf16*  k_bf  = (bf16*)(ws + 100663296);   //  8 MB
  bf16*  vt    = (bf16*)(ws + 109051904);   //  8 MB
  bf16*  ao    = (bf16*)(ws + 117440512);   //  8 MB (total 120 MB)
  float* U  = (float*)(ws + 41943040);      // 16 MB (aliases dead qkv)
  float* ML = (float*)(ws + 58720256);      // 256 KB

  cvt_f32_to_bf16<<<2048, 256, 0, stream>>>(x,      x_bf,  T_DIM * D_DIM / 4);
  cvt_f32_to_bf16<<<2048, 256, 0, stream>>>(W_attn, wa_bf, 3 * D_DIM * D_DIM / 4);
  cvt_f32_to_bf16<<<2048, 256, 0, stream>>>(W_proj, wp_bf, D_DIM * D_DIM / 4);

  gemm256_bt_bias<<<dim3((T_DIM / 256) * (3 * D_DIM / 256)), dim3(512), 0, stream>>>(
      x_bf, wa_bf, b_attn, qkv, T_DIM, 3 * D_DIM, D_DIM);

  ln_rope_kernel<<<(H_DIM * T_DIM) / 4, 256, 0, stream>>>(qkv, q_ln_w, k_ln_w, q_bf, k_bf);
  v_transpose_kernel<<<dim3(T_DIM / 32, C_DIM / 32, H_DIM), dim3(32, 8), 0, stream>>>(qkv, vt);

  attn_kernel<<<dim3(48, H_DIM), 256, 0, stream>>>(q_bf, k_bf, vt, ao, U, ML);
  attn_combine<<<2048, 256, 0, stream>>>(U, ML, ao);

  gemm_bt_bias<<<dim3(D_DIM / 128, T_DIM / 128), 256, 0, stream>>>(
      ao, wp_bf, b_proj, (float*)d_out, T_DIM, D_DIM, D_DIM);
}

// Round 6
// 191.260 us; speedup vs baseline: 1.2616x; 1.0573x over previous
//
#include <hip/hip_runtime.h>
#include <hip/hip_bf16.h>
#include <math.h>

#define T_DIM 2048
#define D_DIM 2048
#define H_DIM 16
#define C_DIM 128

typedef __bf16 bf16;
typedef __attribute__((ext_vector_type(8))) __bf16 bf16x8;
typedef __attribute__((ext_vector_type(4))) __bf16 bf16x4;
typedef __attribute__((ext_vector_type(2))) __bf16 bf16x2;
typedef __attribute__((ext_vector_type(4))) float f32x4;

__device__ __forceinline__ void gload_lds16(const void* g, void* l) {
  __builtin_amdgcn_global_load_lds((__attribute__((address_space(1))) void*)g,
                                   (__attribute__((address_space(3))) void*)l,
                                   16, 0, 0);
}

// ---------------- fused fp32 -> bf16 conversion of x, W_attn, W_proj ----------------
__global__ __launch_bounds__(256) void cvt3(
    const float* __restrict__ x, const float* __restrict__ wa, const float* __restrict__ wp,
    bf16* __restrict__ xo, bf16* __restrict__ wao, bf16* __restrict__ wpo)
{
  const int NX = 1048576, NA = 3145728;      // float4 counts: x, W_attn (W_proj = NX)
  int i = blockIdx.x * 256 + threadIdx.x;
  for (; i < 5242880; i += 2048 * 256) {
    const float* s; bf16* d; int off;
    if (i < NX)            { s = x;  d = xo;  off = i; }
    else if (i < NX + NA)  { s = wa; d = wao; off = i - NX; }
    else                   { s = wp; d = wpo; off = i - NX - NA; }
    float4 v = reinterpret_cast<const float4*>(s)[off];
    bf16x4 o;
    o[0] = (bf16)v.x; o[1] = (bf16)v.y; o[2] = (bf16)v.z; o[3] = (bf16)v.w;
    reinterpret_cast<bf16x4*>(d)[off] = o;
  }
}

// ============ 128x384 4-phase GEMM: C = A(MxK) @ B(NxK)^T + bias (fp32 out) ============
// Grid = (M/128)*(N/384) = 256 blocks -> 100% CU fill. 8 waves as 4M x 2N (per-wave
// 32 x 192). LDS 128 KB: A 2x16 KB + B 2x48 KB (BK=64 dbuf). Phases = 4 N-quadrants of
// 96 cols; per phase stage ONE 128x64 unit (A, B0, B1, B2) via global_load_lds(16B),
// chunk-XOR swizzled (pre-swizzled source, swizzled read; measured 0 conflicts at R4).
// Derived counted waits (reads at phase p are covered by the wait at p-1):
//   P3(t-1) vmcnt(4) -> A(t),B0(t) landed for P0(t) reads
//   P0(t)   vmcnt(4) -> B1(t) landed for P1(t) reads
//   P1(t)   vmcnt(4) -> B2(t) landed for P2(t) reads ; P2 needs no wait.
__global__ __launch_bounds__(512, 2) void gemm384_bt_bias(
    const bf16* __restrict__ A, const bf16* __restrict__ B,
    const float* __restrict__ bias, float* __restrict__ C,
    int M, int N, int K)
{
  __shared__ __align__(16) bf16 Asl[2][128 * 64];  // 32 KB
  __shared__ __align__(16) bf16 Bsl[2][384 * 64];  // 96 KB
  const int tid = threadIdx.x;
  const int lane = tid & 63;
  const int wv = tid >> 6;          // 0..7
  const int g = lane >> 4, r16 = lane & 15;
  const int wm4 = wv >> 1;          // 0..3 : 32-row slice of the 128 M-rows
  const int wn2 = wv & 1;           // 0..1 : 48-col half of each 96-col quadrant

  // XCD swizzle: 256 blocks, 32 contiguous per XCD (2 full A-panel rows each)
  int bid = blockIdx.x;
  int bid2 = (bid & 7) * 32 + (bid >> 3);
  const int ntn = N / 384;
  const int bn = bid2 % ntn, bm = bid2 / ntn;

  const size_t Abase = (size_t)(bm * 128) * K;
  const size_t Bbase = (size_t)(bn * 384) * K;

  f32x4 acc[4][2][3] = {};   // [quadrant][R][F]
  bf16x8 a[2][2], b[3][2];   // [R][ks], [F][ks]

  // stage one 128x64 unit (16 KB = 1024 chunks of 16B = 2 loads/thread)
  auto stageA = [&](int bb, int t) {
#pragma unroll
    for (int i = 0; i < 2; ++i) {
      int c = i * 512 + tid;
      int r = c >> 3, p = c & 7, j = p ^ (r & 7);
      gload_lds16(A + Abase + (size_t)r * K + t * 64 + j * 8,
                  (char*)&Asl[bb][0] + (size_t)c * 16);
    }
  };
  auto stageB = [&](int bb, int u, int t) {   // u = 0..2 -> B rows u*128..+127
#pragma unroll
    for (int i = 0; i < 2; ++i) {
      int c = i * 512 + tid;
      int r = c >> 3, p = c & 7, j = p ^ (r & 7);
      gload_lds16(B + Bbase + (size_t)(u * 128 + r) * K + t * 64 + j * 8,
                  (char*)&Bsl[bb][0] + u * 16384 + (size_t)c * 16);
    }
  };
  auto readA = [&](int bufi) {
#pragma unroll
    for (int R = 0; R < 2; ++R) {
      int ar = wm4 * 32 + R * 16 + r16;
#pragma unroll
      for (int ks = 0; ks < 2; ++ks)
        a[R][ks] = *reinterpret_cast<const bf16x8*>(
            &Asl[bufi][ar * 64 + (((ks * 4 + g) ^ (ar & 7)) << 3)]);
    }
  };
  auto readB = [&](int bufi, int q) {
#pragma unroll
    for (int F = 0; F < 3; ++F) {
      int br = q * 96 + wn2 * 48 + F * 16 + r16;
#pragma unroll
      for (int ks = 0; ks < 2; ++ks)
        b[F][ks] = *reinterpret_cast<const bf16x8*>(
            &Bsl[bufi][br * 64 + (((ks * 4 + g) ^ (br & 7)) << 3)]);
    }
  };
  auto mfma12 = [&](f32x4 (&cq)[2][3]) {
    __builtin_amdgcn_s_setprio(1);
#pragma unroll
    for (int ks = 0; ks < 2; ++ks)
#pragma unroll
      for (int R = 0; R < 2; ++R)
#pragma unroll
        for (int F = 0; F < 3; ++F)
          cq[R][F] = __builtin_amdgcn_mfma_f32_16x16x32_bf16(a[R][ks], b[F][ks], cq[R][F], 0, 0, 0);
    __builtin_amdgcn_s_setprio(0);
  };

#define VMSYNC(VM)                                                \
  asm volatile("s_waitcnt vmcnt(" #VM ")" ::: "memory");          \
  __builtin_amdgcn_s_barrier();                                   \
  asm volatile("s_waitcnt lgkmcnt(0)" ::: "memory");              \
  __builtin_amdgcn_sched_barrier(0);
#define BARSYNC()                                                 \
  __builtin_amdgcn_s_barrier();                                   \
  asm volatile("s_waitcnt lgkmcnt(0)" ::: "memory");              \
  __builtin_amdgcn_sched_barrier(0);

  // prologue: all 4 units of tile 0
  stageA(0, 0); stageB(0, 0, 0); stageB(0, 1, 0); stageB(0, 2, 0);
  asm volatile("s_waitcnt vmcnt(4)" ::: "memory");  // A(0), B0(0) landed
  __builtin_amdgcn_s_barrier();

  const int NT = K >> 6;
  for (int t = 0; t < NT; ++t) {
    const int cb = t & 1, nb = cb ^ 1;
    const bool pf = (t + 1 < NT);
    // P0: quadrant 0 (cols 0-95, in B0); stage A(t+1)
    readA(cb);
    readB(cb, 0);
    if (pf) stageA(nb, t + 1);
    VMSYNC(4)                    // forces B1(t) landed (P1 reads it)
    mfma12(acc[0]);
    __builtin_amdgcn_s_barrier();
    // P1: quadrant 1 (cols 96-191, in B0|B1); stage B0(t+1)
    readB(cb, 1);
    if (pf) stageB(nb, 0, t + 1);
    VMSYNC(4)                    // forces B2(t) landed (P2 reads it)
    mfma12(acc[1]);
    __builtin_amdgcn_s_barrier();
    // P2: quadrant 2 (cols 192-287, in B1|B2); stage B1(t+1)
    readB(cb, 2);
    if (pf) stageB(nb, 1, t + 1);
    BARSYNC()                    // no vmcnt: P3's operands (B2(t)) already guaranteed
    mfma12(acc[2]);
    __builtin_amdgcn_s_barrier();
    // P3: quadrant 3 (cols 288-383, in B2); stage B2(t+1)
    readB(cb, 3);
    if (pf) stageB(nb, 2, t + 1);
    VMSYNC(4)                    // forces A(t+1), B0(t+1) landed (next P0 reads them)
    mfma12(acc[3]);
    __builtin_amdgcn_s_barrier();
  }
#undef VMSYNC
#undef BARSYNC

  // epilogue: bias + fp32 store
#pragma unroll
  for (int q = 0; q < 4; ++q)
#pragma unroll
    for (int R = 0; R < 2; ++R)
#pragma unroll
      for (int F = 0; F < 3; ++F) {
        int row0 = bm * 128 + wm4 * 32 + R * 16 + g * 4;
        int col  = bn * 384 + q * 96 + wn2 * 48 + F * 16 + r16;
        float bv = bias[col];
#pragma unroll
        for (int rr = 0; rr < 4; ++rr)
          C[(size_t)(row0 + rr) * N + col] = acc[q][R][F][rr] + bv;
      }
}

// ---------------- 128x128 GEMM (2-phase dbuf): C = A @ B^T + bias ----------------
__global__ __launch_bounds__(256) void gemm_bt_bias(
    const bf16* __restrict__ A, const bf16* __restrict__ B,
    const float* __restrict__ bias, float* __restrict__ C,
    int M, int N, int K)
{
  __shared__ __align__(16) bf16 As[2][128 * 32];
  __shared__ __align__(16) bf16 Bs[2][128 * 32];
  const int tid = threadIdx.x;
  const int lane = tid & 63;
  const int w = tid >> 6;
  const int wm = (w >> 1) * 64, wn = (w & 1) * 64;
  const int g = lane >> 4;
  const int r16 = lane & 15;
  const int bm = blockIdx.y, bn = blockIdx.x;

  f32x4 acc[4][4] = {};

  const size_t Abase = (size_t)(bm * 128) * K;
  const size_t Bbase = (size_t)(bn * 128) * K;

  auto stage = [&](int bb, int k0) {
#pragma unroll
    for (int c = 0; c < 2; ++c) {
      int e = c * 256 + tid;
      int row = e >> 2, col = (e & 3) * 8;
      gload_lds16(A + Abase + (size_t)row * K + k0 + col, (char*)&As[bb][0] + (size_t)e * 16);
      gload_lds16(B + Bbase + (size_t)row * K + k0 + col, (char*)&Bs[bb][0] + (size_t)e * 16);
    }
  };

  stage(0, 0);
  __syncthreads();

  for (int k0 = 0; k0 < K; k0 += 32) {
    const int cur = (k0 >> 5) & 1;
    if (k0 + 32 < K) stage(cur ^ 1, k0 + 32);
    bf16x8 a[4], b[4];
#pragma unroll
    for (int m = 0; m < 4; ++m)
      a[m] = *reinterpret_cast<const bf16x8*>(&As[cur][(wm + m * 16 + r16) * 32 + g * 8]);
#pragma unroll
    for (int n = 0; n < 4; ++n)
      b[n] = *reinterpret_cast<const bf16x8*>(&Bs[cur][(wn + n * 16 + r16) * 32 + g * 8]);
    __builtin_amdgcn_s_setprio(1);
#pragma unroll
    for (int m = 0; m < 4; ++m)
#pragma unroll
      for (int n = 0; n < 4; ++n)
        acc[m][n] = __builtin_amdgcn_mfma_f32_16x16x32_bf16(a[m], b[n], acc[m][n], 0, 0, 0);
    __builtin_amdgcn_s_setprio(0);
    __syncthreads();
  }

#pragma unroll
  for (int m = 0; m < 4; ++m) {
    int row0 = bm * 128 + wm + m * 16 + g * 4;
#pragma unroll
    for (int n = 0; n < 4; ++n) {
      int col = bn * 128 + wn + n * 16 + r16;
      float bv = bias[col];
#pragma unroll
      for (int rr = 0; rr < 4; ++rr)
        C[(size_t)(row0 + rr) * N + col] = acc[m][n][rr] + bv;
    }
  }
}

// -------- fused LayerNorm+RoPE (blocks 0..8191) + V transpose (blocks 8192..12287) ----
__global__ __launch_bounds__(256) void lnrope_vt_kernel(
    const float* __restrict__ qkv, const float* __restrict__ qw,
    const float* __restrict__ kw, bf16* __restrict__ qo, bf16* __restrict__ ko,
    bf16* __restrict__ vt)
{
  __shared__ bf16 tile[32][33];
  const int tid = threadIdx.x;
  if (blockIdx.x < 8192) {
    // ---- LayerNorm + RoPE on q,k ----
    const int lane = tid & 63;
    const int wid = blockIdx.x * 4 + (tid >> 6);
    const int h = wid >> 11;
    const int t = wid & (T_DIM - 1);
    const int c0 = lane * 2;

    float inv_freq = exp2f(-13.287712379549449f * (float)c0 * (1.0f / 128.0f));
    float fr = (float)t * inv_freq;
    float sn = sinf(fr), cs = cosf(fr);
    const float scaleq = 0.08838834764831845f; // 1/sqrt(128)

#pragma unroll
    for (int which = 0; which < 2; ++which) {
      const float* base = qkv + (size_t)t * (3 * D_DIM) + which * D_DIM + h * C_DIM;
      float2 v = *reinterpret_cast<const float2*>(base + c0);
      float s = v.x + v.y;
#pragma unroll
      for (int m = 32; m; m >>= 1) s += __shfl_xor(s, m);
      float mu = s * (1.0f / 128.0f);
      float d0 = v.x - mu, d1 = v.y - mu;
      float ss = d0 * d0 + d1 * d1;
#pragma unroll
      for (int m = 32; m; m >>= 1) ss += __shfl_xor(ss, m);
      float rstd = rsqrtf(ss * (1.0f / 128.0f) + 1e-6f);
      const float* wgt = which ? kw : qw;
      float x0 = d0 * rstd * wgt[c0], x1 = d1 * rstd * wgt[c0 + 1];
      float o0 = x0 * cs - x1 * sn;
      float o1 = x1 * cs + x0 * sn;
      if (!which) { o0 *= scaleq; o1 *= scaleq; }
      bf16* out = (which ? ko : qo) + ((size_t)h * T_DIM + t) * C_DIM + c0;
      bf16x2 ob; ob[0] = (bf16)o0; ob[1] = (bf16)o1;
      *reinterpret_cast<bf16x2*>(out) = ob;
    }
  } else {
    // ---- V transpose: qkv v-part (t,c) -> vt bf16 [h][c][t] ----
    const int vb = blockIdx.x - 8192;          // 64 x 4 x 16
    const int t0 = (vb & 63) * 32;
    const int c0 = ((vb >> 6) & 3) * 32;
    const int h = vb >> 8;
    const int tx = tid & 31, ty = tid >> 5;
#pragma unroll
    for (int i = 0; i < 4; ++i) {
      int t = t0 + ty + i * 8;
      tile[ty + i * 8][tx] =
          (bf16)qkv[(size_t)t * (3 * D_DIM) + 2 * D_DIM + h * C_DIM + c0 + tx];
    }
    __syncthreads();
#pragma unroll
    for (int i = 0; i < 4; ++i) {
      int c = c0 + ty + i * 8;
      vt[((size_t)h * C_DIM + c) * T_DIM + t0 + tx] = tile[tx][ty + i * 8];
    }
  }
}

// ---------------- Flash attention (causal), swapped-QK^T lane-local softmax ----------
__global__ __launch_bounds__(256, 4) void attn_kernel(
    const bf16* __restrict__ Q, const bf16* __restrict__ K,
    const bf16* __restrict__ VT, bf16* __restrict__ AO,
    float* __restrict__ U, float* __restrict__ ML)
{
  __shared__ __align__(16) bf16 Ks[2][32 * 128];   // 16 KB
  __shared__ __align__(16) bf16 Vs[2][128 * 32];   // 16 KB
  __shared__ __align__(16) bf16 p_lds[4][16 * 32]; //  4 KB
  const int tid = threadIdx.x;
  const int lane = tid & 63;
  const int w = tid >> 6;
  const int g = lane >> 4, r16 = lane & 15;
  const int h = blockIdx.y;
  const int b = blockIdx.x;

  int qb, kb0, kb1, sp;
  if (b < 32) { qb = 16 + (b >> 1); sp = b & 1; kb0 = sp * 32; kb1 = sp ? (2 * qb + 2) : 32; }
  else        { qb = 47 - b;        sp = -1;    kb0 = 0;       kb1 = 2 * qb + 2; }
  const int qr0 = qb * 64 + w * 16;
  const int qrow = qr0 + r16;   // this lane's q-row

  const bf16* Qh = Q + (size_t)h * T_DIM * C_DIM;
  const bf16* Kh = K + (size_t)h * T_DIM * C_DIM;
  const bf16* Vh = VT + (size_t)h * C_DIM * T_DIM;

  bf16x8 qf[4];
#pragma unroll
  for (int kk = 0; kk < 4; ++kk)
    qf[kk] = *reinterpret_cast<const bf16x8*>(
        &Qh[(size_t)qrow * C_DIM + kk * 32 + g * 8]);

  float mrow = -INFINITY, lrow = 0.f;
  f32x4 o[8] = {};

  auto stage = [&](int bb, int kb) {
    const bf16* Kt = Kh + (size_t)(kb * 32) * C_DIM;
    const bf16* Vt = Vh + kb * 32;
#pragma unroll
    for (int i = 0; i < 2; ++i) {
      int e = i * 256 + tid;
      int r = e >> 4, p = e & 15, j = p ^ (r & 7);
      gload_lds16(Kt + r * C_DIM + j * 8, (char*)&Ks[bb][0] + (size_t)e * 16);
    }
#pragma unroll
    for (int i = 0; i < 2; ++i) {
      int e = i * 256 + tid;
      int r = e >> 2, p = e & 3, j = p ^ ((r >> 1) & 3);
      gload_lds16(Vt + (size_t)r * T_DIM + j * 8, (char*)&Vs[bb][0] + (size_t)e * 16);
    }
  };

  stage(0, kb0);
  __syncthreads();
  int buf = 0;

  for (int kb = kb0; kb < kb1; ++kb) {
    if (kb + 1 < kb1) stage(buf ^ 1, kb + 1);

    f32x4 sacc[2] = {};
    __builtin_amdgcn_s_setprio(1);
#pragma unroll
    for (int n = 0; n < 2; ++n) {
      int kr = n * 16 + r16;
      const bf16* kbase = &Ks[buf][kr << 7];
#pragma unroll
      for (int kk = 0; kk < 4; ++kk) {
        bf16x8 kf = *reinterpret_cast<const bf16x8*>(
            kbase + (((kk * 4 + g) ^ (kr & 7)) << 3));
        sacc[n] = __builtin_amdgcn_mfma_f32_16x16x32_bf16(kf, qf[kk], sacc[n], 0, 0, 0);
      }
    }
    __builtin_amdgcn_s_setprio(0);
    if (kb * 32 + 31 > qr0) {
#pragma unroll
      for (int n = 0; n < 2; ++n)
#pragma unroll
        for (int rr = 0; rr < 4; ++rr)
          if (kb * 32 + n * 16 + g * 4 + rr > qrow) sacc[n][rr] = -3.0e38f;
    }
    float mx = fmaxf(fmaxf(fmaxf(sacc[0][0], sacc[0][1]), fmaxf(sacc[0][2], sacc[0][3])),
                     fmaxf(fmaxf(sacc[1][0], sacc[1][1]), fmaxf(sacc[1][2], sacc[1][3])));
    mx = fmaxf(mx, __shfl_xor(mx, 16));
    mx = fmaxf(mx, __shfl_xor(mx, 32));
    float alpha = 1.0f;
    bool need = __any(mx > mrow + 8.0f);
    if (need) {
      float mnew = fmaxf(mrow, mx);
      alpha = __expf(mrow - mnew);
      mrow = mnew;
    }
    float ps = 0.f;
#pragma unroll
    for (int n = 0; n < 2; ++n)
#pragma unroll
      for (int rr = 0; rr < 4; ++rr) {
        float p = __expf(sacc[n][rr] - mrow);
        sacc[n][rr] = p;
        ps += p;
      }
    ps += __shfl_xor(ps, 16);
    ps += __shfl_xor(ps, 32);
    lrow = lrow * alpha + ps;
    if (need) {
#pragma unroll
      for (int nc = 0; nc < 8; ++nc)
#pragma unroll
        for (int rr = 0; rr < 4; ++rr)
          o[nc][rr] *= alpha;
    }
    {
      bf16* prow = &p_lds[w][r16 << 5];
      const int ssw = (r16 >> 1) & 3;
#pragma unroll
      for (int n = 0; n < 2; ++n) {
        bf16x4 pk;
        pk[0] = (bf16)sacc[n][0]; pk[1] = (bf16)sacc[n][1];
        pk[2] = (bf16)sacc[n][2]; pk[3] = (bf16)sacc[n][3];
        int c8 = 2 * n + (g >> 1);
        *reinterpret_cast<bf16x4*>(prow + (((c8 ^ ssw) << 3) | ((g & 1) << 2))) = pk;
      }
    }
    asm volatile("s_waitcnt lgkmcnt(0)" ::: "memory");
    __builtin_amdgcn_s_setprio(1);
    bf16x8 pf = *reinterpret_cast<const bf16x8*>(
        &p_lds[w][(r16 << 5) + ((g ^ ((r16 >> 1) & 3)) << 3)]);
#pragma unroll
    for (int nc = 0; nc < 8; ++nc) {
      int vr = nc * 16 + r16;
      bf16x8 vf = *reinterpret_cast<const bf16x8*>(
          &Vs[buf][(vr << 5) + ((g ^ ((vr >> 1) & 3)) << 3)]);
      o[nc] = __builtin_amdgcn_mfma_f32_16x16x32_bf16(vf, pf, o[nc], 0, 0, 0);
    }
    __builtin_amdgcn_s_setprio(0);
    __syncthreads();
    buf ^= 1;
  }

  if (sp < 0) {
    float inv = 1.0f / lrow;
    bf16* arow = &AO[(size_t)qrow * D_DIM + h * C_DIM + (g << 2)];
#pragma unroll
    for (int nc = 0; nc < 8; ++nc) {
      bf16x4 ob;
      ob[0] = (bf16)(o[nc][0] * inv); ob[1] = (bf16)(o[nc][1] * inv);
      ob[2] = (bf16)(o[nc][2] * inv); ob[3] = (bf16)(o[nc][3] * inv);
      *reinterpret_cast<bf16x4*>(arow + nc * 16) = ob;
    }
  } else {
    const int qi = qb - 16;
    const size_t ubase = ((size_t)(h * 16 + qi) * 2 + sp) * (64 * 128);
    const size_t mlbase = (size_t)(h * 16 + qi) * 256 + sp * 128;
    const int row = w * 16 + r16;
    float* urow = &U[ubase + (size_t)row * 128 + (g << 2)];
#pragma unroll
    for (int nc = 0; nc < 8; ++nc)
      *reinterpret_cast<f32x4*>(urow + nc * 16) = o[nc];
    if (g == 0) {
      ML[mlbase + row] = mrow;
      ML[mlbase + 64 + row] = lrow;
    }
  }
}

// ---------------- combine: merge the two KV-split partials for qb>=16 ----------------
__global__ __launch_bounds__(256) void attn_combine(
    const float* __restrict__ U, const float* __restrict__ ML, bf16* __restrict__ AO)
{
  int idx = blockIdx.x * 256 + threadIdx.x;
  int c4 = (idx & 31) * 4;
  int r = idx >> 5;
  int trow = r & 63;
  int qi = (r >> 6) & 15;
  int h = r >> 10;

  size_t mlbase = (size_t)(h * 16 + qi) * 256;
  float m0 = ML[mlbase + trow],       l0 = ML[mlbase + 64 + trow];
  float m1 = ML[mlbase + 128 + trow], l1 = ML[mlbase + 192 + trow];
  float m = fmaxf(m0, m1);
  float a0 = __expf(m0 - m), a1 = __expf(m1 - m);
  float inv = 1.0f / (l0 * a0 + l1 * a1);

  size_t t0 = ((size_t)(h * 16 + qi) * 2) * (64 * 128) + (size_t)trow * 128 + c4;
  float4 u0 = *reinterpret_cast<const float4*>(U + t0);
  float4 u1 = *reinterpret_cast<const float4*>(U + t0 + 64 * 128);
  int t = 1024 + qi * 64 + trow;
  bf16x4 ob;
  ob[0] = (bf16)((u0.x * a0 + u1.x * a1) * inv);
  ob[1] = (bf16)((u0.y * a0 + u1.y * a1) * inv);
  ob[2] = (bf16)((u0.z * a0 + u1.z * a1) * inv);
  ob[3] = (bf16)((u0.w * a0 + u1.w * a1) * inv);
  *reinterpret_cast<bf16x4*>(&AO[(size_t)t * D_DIM + h * C_DIM + c4]) = ob;
}

// ---------------- launch ----------------
extern "C" void kernel_launch(void* const* d_in, const int* in_sizes, int n_in,
                              void* d_out, int out_size, void* d_ws, size_t ws_size,
                              hipStream_t stream)
{
  const float* x      = (const float*)d_in[0];
  const float* W_attn = (const float*)d_in[1];
  const float* b_attn = (const float*)d_in[2];
  const float* W_proj = (const float*)d_in[3];
  const float* b_proj = (const float*)d_in[4];
  const float* q_ln_w = (const float*)d_in[5];
  const float* k_ln_w = (const float*)d_in[6];

  char* ws = (char*)d_ws;
  bf16*  x_bf  = (bf16*)(ws + 0);           //  8 MB
  bf16*  wa_bf = (bf16*)(ws + 8388608);     // 24 MB
  bf16*  wp_bf = (bf16*)(ws + 33554432);    //  8 MB
  float* qkv   = (float*)(ws + 41943040);   // 48 MB (dead after lnrope_vt)
  bf16*  q_bf  = (bf16*)(ws + 92274688);    //  8 MB
  bf16*  k_bf  = (bf16*)(ws + 100663296);   //  8 MB
  bf16*  vt    = (bf16*)(ws + 109051904);   //  8 MB
  bf16*  ao    = (bf16*)(ws + 117440512);   //  8 MB (total 120 MB)
  float* U  = (float*)(ws + 41943040);      // 16 MB (aliases dead qkv)
  float* ML = (float*)(ws + 58720256);      // 256 KB

  cvt3<<<2048, 256, 0, stream>>>(x, W_attn, W_proj, x_bf, wa_bf, wp_bf);

  gemm384_bt_bias<<<dim3((T_DIM / 128) * (3 * D_DIM / 384)), dim3(512), 0, stream>>>(
      x_bf, wa_bf, b_attn, qkv, T_DIM, 3 * D_DIM, D_DIM);

  lnrope_vt_kernel<<<8192 + 4096, 256, 0, stream>>>(qkv, q_ln_w, k_ln_w, q_bf, k_bf, vt);

  attn_kernel<<<dim3(48, H_DIM), 256, 0, stream>>>(q_bf, k_bf, vt, ao, U, ML);
  attn_combine<<<2048, 256, 0, stream>>>(U, ML, ao);

  gemm_bt_bias<<<dim3(D_DIM / 128, T_DIM / 128), 256, 0, stream>>>(
      ao, wp_bf, b_proj, (float*)d_out, T_DIM, D_DIM, D_DIM);
}

// Round 7
// 187.682 us; speedup vs baseline: 1.2856x; 1.0191x over previous
//
#include <hip/hip_runtime.h>
#include <hip/hip_bf16.h>
#include <math.h>

#define T_DIM 2048
#define D_DIM 2048
#define H_DIM 16
#define C_DIM 128

typedef __bf16 bf16;
typedef __attribute__((ext_vector_type(8))) __bf16 bf16x8;
typedef __attribute__((ext_vector_type(4))) __bf16 bf16x4;
typedef __attribute__((ext_vector_type(2))) __bf16 bf16x2;
typedef __attribute__((ext_vector_type(4))) float f32x4;

__device__ __forceinline__ void gload_lds16(const void* g, void* l) {
  __builtin_amdgcn_global_load_lds((__attribute__((address_space(1))) void*)g,
                                   (__attribute__((address_space(3))) void*)l,
                                   16, 0, 0);
}

// ---------------- fused fp32 -> bf16 conversion of x, W_attn, W_proj ----------------
__global__ __launch_bounds__(256) void cvt3(
    const float* __restrict__ x, const float* __restrict__ wa, const float* __restrict__ wp,
    bf16* __restrict__ xo, bf16* __restrict__ wao, bf16* __restrict__ wpo)
{
  const int NX = 1048576, NA = 3145728;      // float4 counts: x, W_attn (W_proj = NX)
  int i = blockIdx.x * 256 + threadIdx.x;
  for (; i < 5242880; i += 2048 * 256) {
    const float* s; bf16* d; int off;
    if (i < NX)            { s = x;  d = xo;  off = i; }
    else if (i < NX + NA)  { s = wa; d = wao; off = i - NX; }
    else                   { s = wp; d = wpo; off = i - NX - NA; }
    float4 v = reinterpret_cast<const float4*>(s)[off];
    bf16x4 o;
    o[0] = (bf16)v.x; o[1] = (bf16)v.y; o[2] = (bf16)v.z; o[3] = (bf16)v.w;
    reinterpret_cast<bf16x4*>(d)[off] = o;
  }
}

// ============ 128x384 4-phase GEMM: C = A(MxK) @ B(NxK)^T + bias (fp32 out) ============
// Grid = 256 blocks (100% fill), 8 waves as 2M x 4N (per-wave 64x96 -> LDS reads 20 vs
// 48 MFMA per K-tile: MFMA-bound; the R5 4Mx2N layout was LDS-read-bound at 28 reads).
// Phases = per-wave output quadrants in Gray order (0,0),(0,1),(1,1),(1,0); a0/a1/b0/b1
// fragments held in registers across phases. LDS 128 KB (BK=64 dbuf), chunk-XOR swizzle
// (measured 0 conflicts). One vmcnt(0) per K-tile at P3: t+1 units issued P0-P2 get
// >=1.5 phases of landing lead; no per-phase counted waits needed.
__global__ __launch_bounds__(512, 2) void gemm384_bt_bias(
    const bf16* __restrict__ A, const bf16* __restrict__ B,
    const float* __restrict__ bias, float* __restrict__ C,
    int M, int N, int K)
{
  __shared__ __align__(16) bf16 Asl[2][128 * 64];  // 32 KB
  __shared__ __align__(16) bf16 Bsl[2][384 * 64];  // 96 KB
  const int tid = threadIdx.x;
  const int lane = tid & 63;
  const int wv = tid >> 6;          // 0..7
  const int g = lane >> 4, r16 = lane & 15;
  const int wm = wv >> 2;           // 0..1 : 64-row slice
  const int wn = wv & 3;            // 0..3 : 96-col slice

  // XCD swizzle: 256 blocks, 32 contiguous per XCD (2 full A-panel rows each)
  int bid = blockIdx.x;
  int bid2 = (bid & 7) * 32 + (bid >> 3);
  const int ntn = N / 384;
  const int bn = bid2 % ntn, bm = bid2 / ntn;

  const size_t Abase = (size_t)(bm * 128) * K;
  const size_t Bbase = (size_t)(bn * 384) * K;

  f32x4 acc[2][2][2][3] = {};          // [qr][qc][R][F]
  bf16x8 a0[2][2], a1[2][2];           // A row-halves  [R][ks]
  bf16x8 b0[3][2], b1[3][2];           // B col-halves  [F][ks]

  // stage one 128x64 unit (16 KB = 1024 chunks of 16B = 2 loads/thread)
  auto stageA = [&](int bb, int t) {
#pragma unroll
    for (int i = 0; i < 2; ++i) {
      int c = i * 512 + tid;
      int r = c >> 3, p = c & 7, j = p ^ (r & 7);
      gload_lds16(A + Abase + (size_t)r * K + t * 64 + j * 8,
                  (char*)&Asl[bb][0] + (size_t)c * 16);
    }
  };
  auto stageB = [&](int bb, int u, int t) {   // u = 0..2 -> B rows u*128..+127
#pragma unroll
    for (int i = 0; i < 2; ++i) {
      int c = i * 512 + tid;
      int r = c >> 3, p = c & 7, j = p ^ (r & 7);
      gload_lds16(B + Bbase + (size_t)(u * 128 + r) * K + t * 64 + j * 8,
                  (char*)&Bsl[bb][0] + u * 16384 + (size_t)c * 16);
    }
  };
  auto readAh = [&](bf16x8 (&dst)[2][2], int bufi, int qr) {
#pragma unroll
    for (int R = 0; R < 2; ++R) {
      int ar = wm * 64 + qr * 32 + R * 16 + r16;
#pragma unroll
      for (int ks = 0; ks < 2; ++ks)
        dst[R][ks] = *reinterpret_cast<const bf16x8*>(
            &Asl[bufi][ar * 64 + (((ks * 4 + g) ^ (ar & 7)) << 3)]);
    }
  };
  auto readBh = [&](bf16x8 (&dst)[3][2], int bufi, int qc) {
#pragma unroll
    for (int F = 0; F < 3; ++F) {
      int br = wn * 96 + qc * 48 + F * 16 + r16;
#pragma unroll
      for (int ks = 0; ks < 2; ++ks)
        dst[F][ks] = *reinterpret_cast<const bf16x8*>(
            &Bsl[bufi][br * 64 + (((ks * 4 + g) ^ (br & 7)) << 3)]);
    }
  };
  auto mfma12 = [&](f32x4 (&cq)[2][3], bf16x8 (&aa)[2][2], bf16x8 (&bb)[3][2]) {
    __builtin_amdgcn_s_setprio(1);
#pragma unroll
    for (int ks = 0; ks < 2; ++ks)
#pragma unroll
      for (int R = 0; R < 2; ++R)
#pragma unroll
        for (int F = 0; F < 3; ++F)
          cq[R][F] = __builtin_amdgcn_mfma_f32_16x16x32_bf16(aa[R][ks], bb[F][ks], cq[R][F], 0, 0, 0);
    __builtin_amdgcn_s_setprio(0);
  };

#define PHASESYNC()                                               \
  __builtin_amdgcn_s_barrier();                                   \
  asm volatile("s_waitcnt lgkmcnt(0)" ::: "memory");              \
  __builtin_amdgcn_sched_barrier(0);

  // prologue: all 4 units of tile 0
  stageA(0, 0); stageB(0, 0, 0); stageB(0, 1, 0); stageB(0, 2, 0);
  asm volatile("s_waitcnt vmcnt(0)" ::: "memory");
  __builtin_amdgcn_s_barrier();

  const int NT = K >> 6;
  for (int t = 0; t < NT; ++t) {
    const int cb = t & 1, nb = cb ^ 1;
    const bool pf = (t + 1 < NT);
    // P0: quadrant (0,0) — reads A-h0, B-h0; stage A(t+1), B0(t+1)
    readAh(a0, cb, 0);
    readBh(b0, cb, 0);
    if (pf) { stageA(nb, t + 1); stageB(nb, 0, t + 1); }
    PHASESYNC()
    mfma12(acc[0][0], a0, b0);
    __builtin_amdgcn_s_barrier();
    // P1: quadrant (0,1) — reads B-h1 (A-h0 reused); stage B1(t+1)
    readBh(b1, cb, 1);
    if (pf) stageB(nb, 1, t + 1);
    PHASESYNC()
    mfma12(acc[0][1], a0, b1);
    __builtin_amdgcn_s_barrier();
    // P2: quadrant (1,1) — reads A-h1 (B-h1 reused); stage B2(t+1)
    readAh(a1, cb, 1);
    if (pf) stageB(nb, 2, t + 1);
    PHASESYNC()
    mfma12(acc[1][1], a1, b1);
    __builtin_amdgcn_s_barrier();
    // P3: quadrant (1,0) — no reads (A-h1, B-h0 reused); then single per-tile vmcnt
    mfma12(acc[1][0], a1, b0);
    asm volatile("s_waitcnt vmcnt(0)" ::: "memory");   // all t+1 units landed
    __builtin_amdgcn_s_barrier();
  }
#undef PHASESYNC

  // epilogue: bias + fp32 store
#pragma unroll
  for (int qr = 0; qr < 2; ++qr)
#pragma unroll
    for (int qc = 0; qc < 2; ++qc)
#pragma unroll
      for (int R = 0; R < 2; ++R)
#pragma unroll
        for (int F = 0; F < 3; ++F) {
          int row0 = bm * 128 + wm * 64 + qr * 32 + R * 16 + g * 4;
          int col  = bn * 384 + wn * 96 + qc * 48 + F * 16 + r16;
          float bv = bias[col];
#pragma unroll
          for (int rr = 0; rr < 4; ++rr)
            C[(size_t)(row0 + rr) * N + col] = acc[qr][qc][R][F][rr] + bv;
        }
}

// ---------------- 128x128 GEMM (2-phase dbuf): C = A @ B^T + bias ----------------
__global__ __launch_bounds__(256) void gemm_bt_bias(
    const bf16* __restrict__ A, const bf16* __restrict__ B,
    const float* __restrict__ bias, float* __restrict__ C,
    int M, int N, int K)
{
  __shared__ __align__(16) bf16 As[2][128 * 32];
  __shared__ __align__(16) bf16 Bs[2][128 * 32];
  const int tid = threadIdx.x;
  const int lane = tid & 63;
  const int w = tid >> 6;
  const int wm = (w >> 1) * 64, wn = (w & 1) * 64;
  const int g = lane >> 4;
  const int r16 = lane & 15;
  const int bm = blockIdx.y, bn = blockIdx.x;

  f32x4 acc[4][4] = {};

  const size_t Abase = (size_t)(bm * 128) * K;
  const size_t Bbase = (size_t)(bn * 128) * K;

  auto stage = [&](int bb, int k0) {
#pragma unroll
    for (int c = 0; c < 2; ++c) {
      int e = c * 256 + tid;
      int row = e >> 2, col = (e & 3) * 8;
      gload_lds16(A + Abase + (size_t)row * K + k0 + col, (char*)&As[bb][0] + (size_t)e * 16);
      gload_lds16(B + Bbase + (size_t)row * K + k0 + col, (char*)&Bs[bb][0] + (size_t)e * 16);
    }
  };

  stage(0, 0);
  __syncthreads();

  for (int k0 = 0; k0 < K; k0 += 32) {
    const int cur = (k0 >> 5) & 1;
    if (k0 + 32 < K) stage(cur ^ 1, k0 + 32);
    bf16x8 a[4], b[4];
#pragma unroll
    for (int m = 0; m < 4; ++m)
      a[m] = *reinterpret_cast<const bf16x8*>(&As[cur][(wm + m * 16 + r16) * 32 + g * 8]);
#pragma unroll
    for (int n = 0; n < 4; ++n)
      b[n] = *reinterpret_cast<const bf16x8*>(&Bs[cur][(wn + n * 16 + r16) * 32 + g * 8]);
    __builtin_amdgcn_s_setprio(1);
#pragma unroll
    for (int m = 0; m < 4; ++m)
#pragma unroll
      for (int n = 0; n < 4; ++n)
        acc[m][n] = __builtin_amdgcn_mfma_f32_16x16x32_bf16(a[m], b[n], acc[m][n], 0, 0, 0);
    __builtin_amdgcn_s_setprio(0);
    __syncthreads();
  }

#pragma unroll
  for (int m = 0; m < 4; ++m) {
    int row0 = bm * 128 + wm + m * 16 + g * 4;
#pragma unroll
    for (int n = 0; n < 4; ++n) {
      int col = bn * 128 + wn + n * 16 + r16;
      float bv = bias[col];
#pragma unroll
      for (int rr = 0; rr < 4; ++rr)
        C[(size_t)(row0 + rr) * N + col] = acc[m][n][rr] + bv;
    }
  }
}

// -------- fused LayerNorm+RoPE (blocks 0..8191) + V transpose (blocks 8192..12287) ----
__global__ __launch_bounds__(256) void lnrope_vt_kernel(
    const float* __restrict__ qkv, const float* __restrict__ qw,
    const float* __restrict__ kw, bf16* __restrict__ qo, bf16* __restrict__ ko,
    bf16* __restrict__ vt)
{
  __shared__ bf16 tile[32][33];
  const int tid = threadIdx.x;
  if (blockIdx.x < 8192) {
    const int lane = tid & 63;
    const int wid = blockIdx.x * 4 + (tid >> 6);
    const int h = wid >> 11;
    const int t = wid & (T_DIM - 1);
    const int c0 = lane * 2;

    float inv_freq = exp2f(-13.287712379549449f * (float)c0 * (1.0f / 128.0f));
    float fr = (float)t * inv_freq;
    float sn = sinf(fr), cs = cosf(fr);
    const float scaleq = 0.08838834764831845f; // 1/sqrt(128)

#pragma unroll
    for (int which = 0; which < 2; ++which) {
      const float* base = qkv + (size_t)t * (3 * D_DIM) + which * D_DIM + h * C_DIM;
      float2 v = *reinterpret_cast<const float2*>(base + c0);
      float s = v.x + v.y;
#pragma unroll
      for (int m = 32; m; m >>= 1) s += __shfl_xor(s, m);
      float mu = s * (1.0f / 128.0f);
      float d0 = v.x - mu, d1 = v.y - mu;
      float ss = d0 * d0 + d1 * d1;
#pragma unroll
      for (int m = 32; m; m >>= 1) ss += __shfl_xor(ss, m);
      float rstd = rsqrtf(ss * (1.0f / 128.0f) + 1e-6f);
      const float* wgt = which ? kw : qw;
      float x0 = d0 * rstd * wgt[c0], x1 = d1 * rstd * wgt[c0 + 1];
      float o0 = x0 * cs - x1 * sn;
      float o1 = x1 * cs + x0 * sn;
      if (!which) { o0 *= scaleq; o1 *= scaleq; }
      bf16* out = (which ? ko : qo) + ((size_t)h * T_DIM + t) * C_DIM + c0;
      bf16x2 ob; ob[0] = (bf16)o0; ob[1] = (bf16)o1;
      *reinterpret_cast<bf16x2*>(out) = ob;
    }
  } else {
    const int vb = blockIdx.x - 8192;          // 64 x 4 x 16
    const int t0 = (vb & 63) * 32;
    const int c0 = ((vb >> 6) & 3) * 32;
    const int h = vb >> 8;
    const int tx = tid & 31, ty = tid >> 5;
#pragma unroll
    for (int i = 0; i < 4; ++i) {
      int t = t0 + ty + i * 8;
      tile[ty + i * 8][tx] =
          (bf16)qkv[(size_t)t * (3 * D_DIM) + 2 * D_DIM + h * C_DIM + c0 + tx];
    }
    __syncthreads();
#pragma unroll
    for (int i = 0; i < 4; ++i) {
      int c = c0 + ty + i * 8;
      vt[((size_t)h * C_DIM + c) * T_DIM + t0 + tx] = tile[tx][ty + i * 8];
    }
  }
}

// ---------------- Flash attention (causal), swapped-QK^T lane-local softmax ----------
__global__ __launch_bounds__(256, 4) void attn_kernel(
    const bf16* __restrict__ Q, const bf16* __restrict__ K,
    const bf16* __restrict__ VT, bf16* __restrict__ AO,
    float* __restrict__ U, float* __restrict__ ML)
{
  __shared__ __align__(16) bf16 Ks[2][32 * 128];   // 16 KB
  __shared__ __align__(16) bf16 Vs[2][128 * 32];   // 16 KB
  __shared__ __align__(16) bf16 p_lds[4][16 * 32]; //  4 KB
  const int tid = threadIdx.x;
  const int lane = tid & 63;
  const int w = tid >> 6;
  const int g = lane >> 4, r16 = lane & 15;
  const int h = blockIdx.y;
  const int b = blockIdx.x;

  int qb, kb0, kb1, sp;
  if (b < 32) { qb = 16 + (b >> 1); sp = b & 1; kb0 = sp * 32; kb1 = sp ? (2 * qb + 2) : 32; }
  else        { qb = 47 - b;        sp = -1;    kb0 = 0;       kb1 = 2 * qb + 2; }
  const int qr0 = qb * 64 + w * 16;
  const int qrow = qr0 + r16;   // this lane's q-row

  const bf16* Qh = Q + (size_t)h * T_DIM * C_DIM;
  const bf16* Kh = K + (size_t)h * T_DIM * C_DIM;
  const bf16* Vh = VT + (size_t)h * C_DIM * T_DIM;

  bf16x8 qf[4];
#pragma unroll
  for (int kk = 0; kk < 4; ++kk)
    qf[kk] = *reinterpret_cast<const bf16x8*>(
        &Qh[(size_t)qrow * C_DIM + kk * 32 + g * 8]);

  float mrow = -INFINITY, lrow = 0.f;
  f32x4 o[8] = {};

  auto stage = [&](int bb, int kb) {
    const bf16* Kt = Kh + (size_t)(kb * 32) * C_DIM;
    const bf16* Vt = Vh + kb * 32;
#pragma unroll
    for (int i = 0; i < 2; ++i) {
      int e = i * 256 + tid;
      int r = e >> 4, p = e & 15, j = p ^ (r & 7);
      gload_lds16(Kt + r * C_DIM + j * 8, (char*)&Ks[bb][0] + (size_t)e * 16);
    }
#pragma unroll
    for (int i = 0; i < 2; ++i) {
      int e = i * 256 + tid;
      int r = e >> 2, p = e & 3, j = p ^ ((r >> 1) & 3);
      gload_lds16(Vt + (size_t)r * T_DIM + j * 8, (char*)&Vs[bb][0] + (size_t)e * 16);
    }
  };

  stage(0, kb0);
  __syncthreads();
  int buf = 0;

  for (int kb = kb0; kb < kb1; ++kb) {
    if (kb + 1 < kb1) stage(buf ^ 1, kb + 1);

    f32x4 sacc[2] = {};
    __builtin_amdgcn_s_setprio(1);
#pragma unroll
    for (int n = 0; n < 2; ++n) {
      int kr = n * 16 + r16;
      const bf16* kbase = &Ks[buf][kr << 7];
#pragma unroll
      for (int kk = 0; kk < 4; ++kk) {
        bf16x8 kf = *reinterpret_cast<const bf16x8*>(
            kbase + (((kk * 4 + g) ^ (kr & 7)) << 3));
        sacc[n] = __builtin_amdgcn_mfma_f32_16x16x32_bf16(kf, qf[kk], sacc[n], 0, 0, 0);
      }
    }
    __builtin_amdgcn_s_setprio(0);
    if (kb * 32 + 31 > qr0) {
#pragma unroll
      for (int n = 0; n < 2; ++n)
#pragma unroll
        for (int rr = 0; rr < 4; ++rr)
          if (kb * 32 + n * 16 + g * 4 + rr > qrow) sacc[n][rr] = -3.0e38f;
    }
    float mx = fmaxf(fmaxf(fmaxf(sacc[0][0], sacc[0][1]), fmaxf(sacc[0][2], sacc[0][3])),
                     fmaxf(fmaxf(sacc[1][0], sacc[1][1]), fmaxf(sacc[1][2], sacc[1][3])));
    mx = fmaxf(mx, __shfl_xor(mx, 16));
    mx = fmaxf(mx, __shfl_xor(mx, 32));
    float alpha = 1.0f;
    bool need = __any(mx > mrow + 8.0f);
    if (need) {
      float mnew = fmaxf(mrow, mx);
      alpha = __expf(mrow - mnew);
      mrow = mnew;
    }
    float ps = 0.f;
#pragma unroll
    for (int n = 0; n < 2; ++n)
#pragma unroll
      for (int rr = 0; rr < 4; ++rr) {
        float p = __expf(sacc[n][rr] - mrow);
        sacc[n][rr] = p;
        ps += p;
      }
    ps += __shfl_xor(ps, 16);
    ps += __shfl_xor(ps, 32);
    lrow = lrow * alpha + ps;
    if (need) {
#pragma unroll
      for (int nc = 0; nc < 8; ++nc)
#pragma unroll
        for (int rr = 0; rr < 4; ++rr)
          o[nc][rr] *= alpha;
    }
    {
      bf16* prow = &p_lds[w][r16 << 5];
      const int ssw = (r16 >> 1) & 3;
#pragma unroll
      for (int n = 0; n < 2; ++n) {
        bf16x4 pk;
        pk[0] = (bf16)sacc[n][0]; pk[1] = (bf16)sacc[n][1];
        pk[2] = (bf16)sacc[n][2]; pk[3] = (bf16)sacc[n][3];
        int c8 = 2 * n + (g >> 1);
        *reinterpret_cast<bf16x4*>(prow + (((c8 ^ ssw) << 3) | ((g & 1) << 2))) = pk;
      }
    }
    asm volatile("s_waitcnt lgkmcnt(0)" ::: "memory");
    __builtin_amdgcn_s_setprio(1);
    bf16x8 pf = *reinterpret_cast<const bf16x8*>(
        &p_lds[w][(r16 << 5) + ((g ^ ((r16 >> 1) & 3)) << 3)]);
#pragma unroll
    for (int nc = 0; nc < 8; ++nc) {
      int vr = nc * 16 + r16;
      bf16x8 vf = *reinterpret_cast<const bf16x8*>(
          &Vs[buf][(vr << 5) + ((g ^ ((vr >> 1) & 3)) << 3)]);
      o[nc] = __builtin_amdgcn_mfma_f32_16x16x32_bf16(vf, pf, o[nc], 0, 0, 0);
    }
    __builtin_amdgcn_s_setprio(0);
    __syncthreads();
    buf ^= 1;
  }

  if (sp < 0) {
    float inv = 1.0f / lrow;
    bf16* arow = &AO[(size_t)qrow * D_DIM + h * C_DIM + (g << 2)];
#pragma unroll
    for (int nc = 0; nc < 8; ++nc) {
      bf16x4 ob;
      ob[0] = (bf16)(o[nc][0] * inv); ob[1] = (bf16)(o[nc][1] * inv);
      ob[2] = (bf16)(o[nc][2] * inv); ob[3] = (bf16)(o[nc][3] * inv);
      *reinterpret_cast<bf16x4*>(arow + nc * 16) = ob;
    }
  } else {
    const int qi = qb - 16;
    const size_t ubase = ((size_t)(h * 16 + qi) * 2 + sp) * (64 * 128);
    const size_t mlbase = (size_t)(h * 16 + qi) * 256 + sp * 128;
    const int row = w * 16 + r16;
    float* urow = &U[ubase + (size_t)row * 128 + (g << 2)];
#pragma unroll
    for (int nc = 0; nc < 8; ++nc)
      *reinterpret_cast<f32x4*>(urow + nc * 16) = o[nc];
    if (g == 0) {
      ML[mlbase + row] = mrow;
      ML[mlbase + 64 + row] = lrow;
    }
  }
}

// ---------------- combine: merge the two KV-split partials for qb>=16 ----------------
__global__ __launch_bounds__(256) void attn_combine(
    const float* __restrict__ U, const float* __restrict__ ML, bf16* __restrict__ AO)
{
  int idx = blockIdx.x * 256 + threadIdx.x;
  int c4 = (idx & 31) * 4;
  int r = idx >> 5;
  int trow = r & 63;
  int qi = (r >> 6) & 15;
  int h = r >> 10;

  size_t mlbase = (size_t)(h * 16 + qi) * 256;
  float m0 = ML[mlbase + trow],       l0 = ML[mlbase + 64 + trow];
  float m1 = ML[mlbase + 128 + trow], l1 = ML[mlbase + 192 + trow];
  float m = fmaxf(m0, m1);
  float a0 = __expf(m0 - m), a1 = __expf(m1 - m);
  float inv = 1.0f / (l0 * a0 + l1 * a1);

  size_t t0 = ((size_t)(h * 16 + qi) * 2) * (64 * 128) + (size_t)trow * 128 + c4;
  float4 u0 = *reinterpret_cast<const float4*>(U + t0);
  float4 u1 = *reinterpret_cast<const float4*>(U + t0 + 64 * 128);
  int t = 1024 + qi * 64 + trow;
  bf16x4 ob;
  ob[0] = (bf16)((u0.x * a0 + u1.x * a1) * inv);
  ob[1] = (bf16)((u0.y * a0 + u1.y * a1) * inv);
  ob[2] = (bf16)((u0.z * a0 + u1.z * a1) * inv);
  ob[3] = (bf16)((u0.w * a0 + u1.w * a1) * inv);
  *reinterpret_cast<bf16x4*>(&AO[(size_t)t * D_DIM + h * C_DIM + c4]) = ob;
}

// ---------------- launch ----------------
extern "C" void kernel_launch(void* const* d_in, const int* in_sizes, int n_in,
                              void* d_out, int out_size, void* d_ws, size_t ws_size,
                              hipStream_t stream)
{
  const float* x      = (const float*)d_in[0];
  const float* W_attn = (const float*)d_in[1];
  const float* b_attn = (const float*)d_in[2];
  const float* W_proj = (const float*)d_in[3];
  const float* b_proj = (const float*)d_in[4];
  const float* q_ln_w = (const float*)d_in[5];
  const float* k_ln_w = (const float*)d_in[6];

  char* ws = (char*)d_ws;
  bf16*  x_bf  = (bf16*)(ws + 0);           //  8 MB
  bf16*  wa_bf = (bf16*)(ws + 8388608);     // 24 MB
  bf16*  wp_bf = (bf16*)(ws + 33554432);    //  8 MB
  float* qkv   = (float*)(ws + 41943040);   // 48 MB (dead after lnrope_vt)
  bf16*  q_bf  = (bf16*)(ws + 92274688);    //  8 MB
  bf16*  k_bf  = (bf16*)(ws + 100663296);   //  8 MB
  bf16*  vt    = (bf16*)(ws + 109051904);   //  8 MB
  bf16*  ao    = (bf16*)(ws + 117440512);   //  8 MB (total 120 MB)
  float* U  = (float*)(ws + 41943040);      // 16 MB (aliases dead qkv)
  float* ML = (float*)(ws + 58720256);      // 256 KB

  cvt3<<<2048, 256, 0, stream>>>(x, W_attn, W_proj, x_bf, wa_bf, wp_bf);

  gemm384_bt_bias<<<dim3((T_DIM / 128) * (3 * D_DIM / 384)), dim3(512), 0, stream>>>(
      x_bf, wa_bf, b_attn, qkv, T_DIM, 3 * D_DIM, D_DIM);

  lnrope_vt_kernel<<<8192 + 4096, 256, 0, stream>>>(qkv, q_ln_w, k_ln_w, q_bf, k_bf, vt);

  attn_kernel<<<dim3(48, H_DIM), 256, 0, stream>>>(q_bf, k_bf, vt, ao, U, ML);
  attn_combine<<<2048, 256, 0, stream>>>(U, ML, ao);

  gemm_bt_bias<<<dim3(D_DIM / 128, T_DIM / 128), 256, 0, stream>>>(
      ao, wp_bf, b_proj, (float*)d_out, T_DIM, D_DIM, D_DIM);
}